// Round 5
// baseline (1076.920 us; speedup 1.0000x reference)
//
#include <hip/hip_runtime.h>
#include <math.h>

#define D_MODEL 512
#define N_LAYERS 4
#define LATENT 1024
#define D_INNER 1024
#define D_STATE 16
#define DT_RANK 32
#define KCONV 4
#define BATCH 4
#define SEQ 1024
#define NTOK (BATCH * SEQ) /* 4096 */
#define PCH 32
#define CLEN 32
#define NCAT 1152  /* merged xproj+dt GEMM N: 1024 dt | 32 B/C | 96 pad */

typedef __attribute__((ext_vector_type(8))) short short8;
typedef __attribute__((ext_vector_type(4))) float floatx4;
typedef unsigned short ushort_t;

__device__ __forceinline__ ushort_t f2bf(float f) {
    union { float f; unsigned u; } v; v.f = f;
    unsigned r = v.u + 0x7FFFu + ((v.u >> 16) & 1u);  // RNE
    return (ushort_t)(r >> 16);
}
__device__ __forceinline__ float bf2f(ushort_t u) {
    union { unsigned u; float f; } v; v.u = ((unsigned)u) << 16;
    return v.f;
}

// ---------------------------------------------------------------------------
// bf16 MFMA GEMM, DIRECT global->register (no LDS).
// C[M,N] = A[M,K](bf16) @ Bt[N,K](bf16)^T (+bias)(+C)
// flags: 1 = add bias[n], 2 = accumulate into C (fp32),
//        4 = merged-dt epilogue: n<1024 -> v = softplus(v + bias[n]),
//        8 = write bf16 output to Cb instead of fp32 C.
//
// ROUND-5 THEORY: r0-r4 held ~44us across tile shapes, bank-conflict
// elimination, HBM-traffic halving, barrier removal — the invariant was
// the global->LDS->reg staging round-trip, which for a per-wave-owned
// tile provides ZERO sharing (each fragment is consumed only by the wave
// that staged it) while costing DMA+vmcnt+ds_read+lgkm serialization AND
// capping occupancy via LDS (1.7-5 blocks/CU across rounds).
//
// So: load fragments STRAIGHT from global. For 16x16x32 frags the lane
// address A[(m0+i*16+l16)*lda + kt*64 + ks*32 + quad*8] is a contiguous
// 16B short8 load (global_load_dwordx4); 4-lane quads cover contiguous
// 64B runs. Per-wave load volume identical to the staged version.
//  * Manual 2-deep register double-buffer (static names, rule #20):
//    prefetch distance = one K64 tile = 32 MFMA (~300 cyc) ~ L2 latency.
//  * No barriers, no waitcnt builtins: pure register dataflow; compiler
//    inserts counted vmcnt before first use (G7/m97: it does this well).
//  * No LDS -> occupancy VGPR-limited: ~205 VGPR -> 2 waves/SIMD =
//    8 waves/CU (vs 2-5 before). All grids fit one residency round.
//  * MI template: 4 -> 64-row tile (big-N GEMMs); 2 -> 32-row tile
//    (N=512 GEMMs, doubles grid to 1024 waves, ~140 VGPR -> 3/SIMD).
//  * XCD-chunked bijective remap retained (r3: FETCH 37.6->18 MB).
// ---------------------------------------------------------------------------
template<int MI>
__global__ __launch_bounds__(64, (MI == 4) ? 2 : 3) void gemm_bf16_direct(
    const ushort_t* __restrict__ A, int lda,
    const ushort_t* __restrict__ Bt, int ldb,
    float* __restrict__ C, ushort_t* __restrict__ Cb, int ldc,
    const float* __restrict__ bias,
    int M, int N, int K, int flags)
{
    // XCD-chunked bijective remap (all grids have nwg % 8 == 0).
    const int gx = gridDim.x;
    const int nwg = gx * gridDim.y;
    const int orig = blockIdx.y * gx + blockIdx.x;
    const int qq = nwg >> 3, rr = nwg & 7;
    const int xcd = orig & 7, loc = orig >> 3;
    const int swz = (xcd < rr ? xcd * (qq + 1) : rr * (qq + 1) + (xcd - rr) * qq) + loc;
    const int m0 = (swz / gx) * (MI * 16);
    const int n0 = (swz % gx) * 64;

    const int lane = threadIdx.x;      // 0..63
    const int quad = lane >> 4;
    const int l16 = lane & 15;

    // per-lane fragment base pointers (advance by 128 elems per 2 tiles)
    const ushort_t* pa = A + (size_t)(m0 + l16) * lda + quad * 8;
    const ushort_t* pb = Bt + (size_t)(n0 + l16) * ldb + quad * 8;

    floatx4 acc[MI][4] = {};
    const int nt = K >> 6;   // K = 512 or 1024 -> nt even (8 or 16)

    // two static register sets (rule #20: no runtime indexing)
    short8 sa0[MI][2], sb0[4][2], sa1[MI][2], sb1[4][2];

    // t is a compile-time small offset (0/1/2 tiles from current pa/pb)
    #define LOADT(sa, sb, t)                                                   \
        do {                                                                   \
            _Pragma("unroll")                                                  \
            for (int i = 0; i < MI; i++)                                       \
                _Pragma("unroll")                                              \
                for (int ks = 0; ks < 2; ks++)                                 \
                    sa[i][ks] = *(const short8*)(pa + (size_t)(i * 16) * lda   \
                                                 + (t) * 64 + ks * 32);        \
            _Pragma("unroll")                                                  \
            for (int j = 0; j < 4; j++)                                        \
                _Pragma("unroll")                                              \
                for (int ks = 0; ks < 2; ks++)                                 \
                    sb[j][ks] = *(const short8*)(pb + (size_t)(j * 16) * ldb   \
                                                 + (t) * 64 + ks * 32);        \
        } while (0)

    #define MMT(sa, sb)                                                        \
        do {                                                                   \
            _Pragma("unroll")                                                  \
            for (int ks = 0; ks < 2; ks++)                                     \
                _Pragma("unroll")                                              \
                for (int i = 0; i < MI; i++)                                   \
                    _Pragma("unroll")                                          \
                    for (int j = 0; j < 4; j++)                                \
                        acc[i][j] = __builtin_amdgcn_mfma_f32_16x16x32_bf16(   \
                            sa[i][ks], sb[j][ks], acc[i][j], 0, 0, 0);         \
        } while (0)

    LOADT(sa0, sb0, 0);
    for (int kt = 0; kt < nt; kt += 2) {
        LOADT(sa1, sb1, 1);            // tile kt+1 in flight
        MMT(sa0, sb0);                 // compute tile kt
        if (kt + 2 < nt) LOADT(sa0, sb0, 2);  // tile kt+2 in flight
        MMT(sa1, sb1);                 // compute tile kt+1
        pa += 128;
        pb += 128;
    }
    #undef LOADT
    #undef MMT

    // C/D layout (m89-verified): col = lane&15, row = quad*4 + reg.
    #pragma unroll
    for (int j = 0; j < 4; j++) {
        int n = n0 + j * 16 + l16;
        float bv = (flags & 1) ? bias[n] : 0.f;
        bool do_sp = (flags & 4) && (n < 1024);
        float spb = do_sp ? bias[n] : 0.f;
        #pragma unroll
        for (int i = 0; i < MI; i++) {
            int mrow = m0 + i * 16 + quad * 4;
            #pragma unroll
            for (int rr2 = 0; rr2 < 4; rr2++) {
                size_t idx = (size_t)(mrow + rr2) * ldc + n;
                float v = acc[i][j][rr2] + bv;
                if (do_sp) {
                    v += spb;
                    v = (v > 20.f) ? v : log1pf(__expf(v));
                }
                if (flags & 8) {
                    Cb[idx] = f2bf(v);
                } else {
                    if (flags & 2) v += C[idx];
                    C[idx] = v;
                }
            }
        }
    }
}

// ---------------------------------------------------------------------------
// build_wdt: Wcat rows 0..1023 = (xw[:, :32] @ dt_w)^T, bf16 [n][k].
// ---------------------------------------------------------------------------
__global__ __launch_bounds__(256) void build_wdt_kernel(
    const float* __restrict__ xproj_w, const float* __restrict__ dt_w,
    ushort_t* __restrict__ wcat)
{
    const int l = blockIdx.z;
    const int n0 = blockIdx.x * 64;
    const int k0 = blockIdx.y * 64;
    const float* xw  = xproj_w + (size_t)l * D_INNER * 64;
    const float* dtw = dt_w + (size_t)l * DT_RANK * D_INNER;

    __shared__ float xs[64][33];   // [k][r]
    __shared__ float ds[32][65];   // [r][n]

    const int tid = threadIdx.x;
    {
        int row = tid >> 2;
        int col = (tid & 3) * 8;
        #pragma unroll
        for (int q = 0; q < 8; q++)
            xs[row][col + q] = xw[(size_t)(k0 + row) * 64 + col + q];
    }
    {
        int row = tid >> 3;
        int col = (tid & 7) * 8;
        #pragma unroll
        for (int q = 0; q < 8; q++)
            ds[row][col + q] = dtw[(size_t)row * D_INNER + n0 + col + q];
    }
    __syncthreads();

    const int ty = tid & 15;
    const int tx = tid >> 4;
    float acc[4][4] = {};
    #pragma unroll
    for (int r = 0; r < 32; r++) {
        float a[4], b[4];
        #pragma unroll
        for (int i = 0; i < 4; i++) a[i] = xs[ty * 4 + i][r];
        #pragma unroll
        for (int j = 0; j < 4; j++) b[j] = ds[r][tx * 4 + j];
        #pragma unroll
        for (int j = 0; j < 4; j++)
            #pragma unroll
            for (int i = 0; i < 4; i++)
                acc[j][i] = fmaf(a[i], b[j], acc[j][i]);
    }
    #pragma unroll
    for (int j = 0; j < 4; j++) {
        int n = n0 + tx * 4 + j;
        ushort4 o;
        o.x = f2bf(acc[j][0]); o.y = f2bf(acc[j][1]);
        o.z = f2bf(acc[j][2]); o.w = f2bf(acc[j][3]);
        *(ushort4*)&wcat[((size_t)l * NCAT + n) * D_INNER + k0 + ty * 4] = o;
    }
}

// ---------------------------------------------------------------------------
// build_wbc: Wcat rows 1024..1151: j<32 -> xw[k][32+j] cast; else zero pad.
// (Pad MUST be written every launch: d_ws is re-poisoned to 0xAA.)
// ---------------------------------------------------------------------------
__global__ __launch_bounds__(256) void build_wbc_kernel(
    const float* __restrict__ xproj_w, ushort_t* __restrict__ wcat)
{
    const int idx = blockIdx.x * 256 + threadIdx.x;
    const int k = idx & 1023;
    const int j = (idx >> 10) & 127;
    const int l = idx >> 17;
    ushort_t v = 0;
    if (j < 32)
        v = f2bf(xproj_w[((size_t)l * D_INNER + k) * 64 + 32 + j]);
    wcat[((size_t)l * NCAT + 1024 + j) * D_INNER + k] = v;
}

// ---------------------------------------------------------------------------
__global__ __launch_bounds__(256) void transpose_cast_kernel(
    const float* __restrict__ in, ushort_t* __restrict__ out, int K, int N)
{
    __shared__ float tile[32][33];
    const int n0 = blockIdx.x * 32, k0 = blockIdx.y * 32;
    const int tx = threadIdx.x & 31, ty = threadIdx.x >> 5;
    #pragma unroll
    for (int i = 0; i < 4; i++)
        tile[ty + i * 8][tx] = in[(size_t)(k0 + ty + i * 8) * N + n0 + tx];
    __syncthreads();
    #pragma unroll
    for (int i = 0; i < 4; i++)
        out[(size_t)(n0 + ty + i * 8) * K + k0 + tx] = f2bf(tile[tx][ty + i * 8]);
}

// ---------------------------------------------------------------------------
__global__ __launch_bounds__(256) void cast_bf16_kernel(
    const float* __restrict__ in, ushort_t* __restrict__ out)
{
    const int i = blockIdx.x * 256 + threadIdx.x;
    out[i] = f2bf(in[i]);
}

// ---------------------------------------------------------------------------
__global__ __launch_bounds__(256) void rmsnorm_kernel(
    const float* __restrict__ x, const float* __restrict__ w,
    ushort_t* __restrict__ y)
{
    const int row = blockIdx.x;
    const float* xr = x + (size_t)row * D_MODEL;
    ushort_t* yr = y + (size_t)row * D_MODEL;
    const int tid = threadIdx.x;

    float v0 = xr[tid], v1 = xr[tid + 256];
    float ss = v0 * v0 + v1 * v1;
    #pragma unroll
    for (int off = 32; off > 0; off >>= 1) ss += __shfl_down(ss, off);

    __shared__ float wsum[4];
    __shared__ float scale_s;
    int wid = tid >> 6, lane = tid & 63;
    if (lane == 0) wsum[wid] = ss;
    __syncthreads();
    if (tid == 0) {
        float tot = wsum[0] + wsum[1] + wsum[2] + wsum[3];
        scale_s = 1.0f / sqrtf(tot / (float)D_MODEL + 1e-5f);
    }
    __syncthreads();
    float sc = scale_s;
    yr[tid] = f2bf(v0 * sc * w[tid]);
    yr[tid + 256] = f2bf(v1 * sc * w[tid + 256]);
}

// ---------------------------------------------------------------------------
// Causal dwconv (K=4) + bias + silu. Reads bf16 xz (stride 2048, xp plane),
// writes bf16 u.
// ---------------------------------------------------------------------------
__global__ __launch_bounds__(256) void conv_silu_kernel(
    const ushort_t* __restrict__ xz, const float* __restrict__ w,
    const float* __restrict__ bconv, ushort_t* __restrict__ outb)
{
    const int idx = blockIdx.x * 256 + threadIdx.x;
    const int d = idx & (D_INNER - 1);
    const int t = (idx >> 10) & (SEQ - 1);
    const int row = idx >> 10;
    const ushort_t* base = xz + (size_t)row * 2048 + d;

    float s = 0.f;
    #pragma unroll
    for (int k = 0; k < KCONV; k++) {
        int tt = t + k - (KCONV - 1);
        if (tt >= 0)
            s = fmaf(bf2f(base[(ptrdiff_t)(k - (KCONV - 1)) * 2048]), w[d * KCONV + k], s);
    }
    s += bconv[d];
    float r = s / (1.f + __expf(-s));
    outb[idx] = f2bf(r);
}

// ---------------------------------------------------------------------------
// Chunked selective scan (3 passes), CLEN=32. dt/B/C in dbl (stride NCAT):
// dbl[row][d]=softplus'ed dt; dbl[row][1024+n]=B[n]; dbl[row][1040+n]=C[n].
// u is bf16 in xb; z is bf16 in xz[:,1024:].
// ---------------------------------------------------------------------------
__global__ __launch_bounds__(256) void scan_pass1(
    const float* __restrict__ dbl, const ushort_t* __restrict__ ub,
    const float* __restrict__ A_log,
    float* __restrict__ hfin, float* __restrict__ sumdt)
{
    const int tid = threadIdx.x;
    const int b = blockIdx.x >> 7;
    const int p = (blockIdx.x >> 2) & 31;
    const int d = ((blockIdx.x & 3) << 8) + tid;
    const int t0 = p * CLEN;

    float A[D_STATE];
    #pragma unroll
    for (int n = 0; n < D_STATE; n++) A[n] = -expf(A_log[d * D_STATE + n]);

    float h[D_STATE] = {};
    float sdt = 0.f;

    const float* dtp = dbl + ((size_t)b * SEQ + t0) * NCAT + d;
    const float* bp  = dbl + ((size_t)b * SEQ + t0) * NCAT + 1024;
    const ushort_t* up = ub + ((size_t)b * SEQ + t0) * D_INNER + d;

    for (int t = 0; t < CLEN; t++) {
        float dtv = dtp[(size_t)t * NCAT];
        float uv  = bf2f(up[(size_t)t * D_INNER]);
        float dtu = dtv * uv;
        sdt += dtv;
        #pragma unroll
        for (int n = 0; n < D_STATE; n++)
            h[n] = fmaf(__expf(dtv * A[n]), h[n], dtu * bp[t * NCAT + n]);
    }

    size_t base = (size_t)(b * PCH + p) * D_STATE * D_INNER + d;
    #pragma unroll
    for (int n = 0; n < D_STATE; n++) hfin[base + (size_t)n * D_INNER] = h[n];
    sumdt[(size_t)(b * PCH + p) * D_INNER + d] = sdt;
}

__global__ __launch_bounds__(256) void scan_pass2(
    const float* __restrict__ A_log, const float* __restrict__ sumdt,
    float* __restrict__ hc)
{
    const int tid = threadIdx.x;
    const int b = blockIdx.x >> 6;
    const int n = (blockIdx.x >> 2) & 15;
    const int d = ((blockIdx.x & 3) << 8) + tid;

    const float Aval = -expf(A_log[d * D_STATE + n]);
    float h = 0.f;
    for (int p = 0; p < PCH; p++) {
        size_t idx = ((size_t)(b * PCH + p) * D_STATE + n) * D_INNER + d;
        float fin = hc[idx];
        hc[idx] = h;
        h = fmaf(__expf(Aval * sumdt[(size_t)(b * PCH + p) * D_INNER + d]), h, fin);
    }
}

// pass3: u (bf16, in ub) read then overwritten IN PLACE with y*silu(z).
__global__ __launch_bounds__(256) void scan_pass3(
    const float* __restrict__ dbl, const ushort_t* __restrict__ xz,
    const float* __restrict__ A_log, const float* __restrict__ Dp,
    const float* __restrict__ hstart, ushort_t* ub)
{
    const int tid = threadIdx.x;
    const int b = blockIdx.x >> 7;
    const int p = (blockIdx.x >> 2) & 31;
    const int d = ((blockIdx.x & 3) << 8) + tid;
    const int t0 = p * CLEN;

    float A[D_STATE];
    #pragma unroll
    for (int n = 0; n < D_STATE; n++) A[n] = -expf(A_log[d * D_STATE + n]);
    const float Dv = Dp[d];

    float h[D_STATE];
    size_t base = (size_t)(b * PCH + p) * D_STATE * D_INNER + d;
    #pragma unroll
    for (int n = 0; n < D_STATE; n++) h[n] = hstart[base + (size_t)n * D_INNER];

    const float* dtp = dbl + ((size_t)b * SEQ + t0) * NCAT + d;
    const float* bp  = dbl + ((size_t)b * SEQ + t0) * NCAT + 1024;
    const ushort_t* zp = xz + ((size_t)b * SEQ + t0) * 2048 + 1024 + d;
    ushort_t* up = ub + ((size_t)b * SEQ + t0) * D_INNER + d;

    for (int t = 0; t < CLEN; t++) {
        float dtv = dtp[(size_t)t * NCAT];
        float uv  = bf2f(up[(size_t)t * D_INNER]);
        float zv  = bf2f(zp[(size_t)t * 2048]);
        float dtu = dtv * uv;
        float y = 0.f;
        #pragma unroll
        for (int n = 0; n < D_STATE; n++) {
            h[n] = fmaf(__expf(dtv * A[n]), h[n], dtu * bp[t * NCAT + n]);
            y = fmaf(h[n], bp[t * NCAT + 16 + n], y);
        }
        float res = fmaf(uv, Dv, y);
        res *= zv / (1.f + __expf(-zv));
        up[(size_t)t * D_INNER] = f2bf(res);
    }
}

// ---------------------------------------------------------------------------
__global__ __launch_bounds__(256) void softmax_kernel(
    const float* __restrict__ in, float* __restrict__ out)
{
    const int idx = blockIdx.x * 256 + threadIdx.x;
    float v = in[idx];
    float m = v;
    #pragma unroll
    for (int off = 16; off > 0; off >>= 1) m = fmaxf(m, __shfl_xor(m, off, 32));
    float e = expf(v - m);
    float s = e;
    #pragma unroll
    for (int off = 16; off > 0; off >>= 1) s += __shfl_xor(s, off, 32);
    out[idx] = e / s;
}

// ---------------------------------------------------------------------------
extern "C" void kernel_launch(void* const* d_in, const int* in_sizes, int n_in,
                              void* d_out, int out_size, void* d_ws, size_t ws_size,
                              hipStream_t stream)
{
    const float* x       = (const float*)d_in[0];
    const float* lin1_w  = (const float*)d_in[1];
    const float* lin1_b  = (const float*)d_in[2];
    const float* norm_w  = (const float*)d_in[3];
    const float* in_w    = (const float*)d_in[4];
    const float* conv_w  = (const float*)d_in[5];
    const float* conv_b  = (const float*)d_in[6];
    const float* xproj_w = (const float*)d_in[7];
    const float* dt_w    = (const float*)d_in[8];
    const float* dt_b    = (const float*)d_in[9];
    const float* A_log   = (const float*)d_in[10];
    const float* Dp      = (const float*)d_in[11];
    const float* out_w   = (const float*)d_in[12];
    const float* lin2_w  = (const float*)d_in[13];
    const float* lin2_b  = (const float*)d_in[14];
    float* outp = (float*)d_out;
    (void)ws_size; (void)in_sizes; (void)n_in; (void)out_size;

    float* ws = (float*)d_ws;
    const size_t F1M = 1u << 20;
    float* h     = ws;                        // 2M fl
    float* dbl   = h + 2 * F1M;               // 4.5M fl (also lin2 logits)
    float* sumdt = dbl + (size_t)NTOK * NCAT; // 128K fl
    float* hfin  = sumdt + (size_t)BATCH * PCH * D_INNER; // 2M fl
    ushort_t* xzb   = (ushort_t*)(hfin + 2 * F1M);        // 8M us (xp|z, 2048)
    ushort_t* hn_bf = xzb + 8 * F1M;                      // 2M us
    ushort_t* xb    = hn_bf + 2 * F1M;                    // 4M us
    ushort_t* lin1_wt = xb + 4 * F1M;                     // 512*1024
    ushort_t* in_wt   = lin1_wt + (size_t)512 * 1024;     // 4*2048*512
    ushort_t* out_wt  = in_wt + (size_t)4 * 2048 * 512;   // 4*512*1024
    ushort_t* lin2_wt = out_wt + (size_t)4 * 512 * 1024;  // 1024*512
    ushort_t* wcat    = lin2_wt + (size_t)1024 * 512;     // 4*1152*1024

    dim3 blk(256);
    dim3 wblk(64);

    // --- weight prep ---
    transpose_cast_kernel<<<dim3(512 / 32, 1024 / 32), blk, 0, stream>>>(
        lin1_w, lin1_wt, LATENT, D_MODEL);
    for (int l = 0; l < N_LAYERS; l++) {
        transpose_cast_kernel<<<dim3(2048 / 32, 512 / 32), blk, 0, stream>>>(
            in_w + (size_t)l * 512 * 2048, in_wt + (size_t)l * 2048 * 512, 512, 2048);
        transpose_cast_kernel<<<dim3(512 / 32, 1024 / 32), blk, 0, stream>>>(
            out_w + (size_t)l * 1024 * 512, out_wt + (size_t)l * 512 * 1024, 1024, 512);
    }
    transpose_cast_kernel<<<dim3(1024 / 32, 512 / 32), blk, 0, stream>>>(
        lin2_w, lin2_wt, D_MODEL, LATENT);
    build_wdt_kernel<<<dim3(16, 16, N_LAYERS), blk, 0, stream>>>(
        xproj_w, dt_w, wcat);
    build_wbc_kernel<<<dim3((N_LAYERS * 128 * 1024) / 256), blk, 0, stream>>>(
        xproj_w, wcat);

    // x -> bf16
    cast_bf16_kernel<<<dim3((NTOK * LATENT) / 256), blk, 0, stream>>>(x, xb);

    // lin1: h = x_bf @ lin1_wt^T + b  (fp32 out; 32-row waves, 8x128=1024)
    gemm_bf16_direct<2><<<dim3(D_MODEL / 64, NTOK / 32), wblk, 0, stream>>>(
        xb, LATENT, lin1_wt, LATENT, h, nullptr, D_MODEL, lin1_b,
        NTOK, D_MODEL, LATENT, 1);

    for (int l = 0; l < N_LAYERS; l++) {
        const float* nw = norm_w + (size_t)l * D_MODEL;
        const float* cw = conv_w + (size_t)l * D_INNER * KCONV;
        const float* cb = conv_b + (size_t)l * D_INNER;
        const float* db = dt_b + (size_t)l * D_INNER;
        const float* al = A_log + (size_t)l * D_INNER * D_STATE;
        const float* dp = Dp + (size_t)l * D_INNER;
        const ushort_t* iwt = in_wt + (size_t)l * 2048 * 512;
        const ushort_t* owt = out_wt + (size_t)l * 512 * 1024;
        const ushort_t* wc  = wcat + (size_t)l * NCAT * D_INNER;

        rmsnorm_kernel<<<dim3(NTOK), blk, 0, stream>>>(h, nw, hn_bf);

        // fused in-proj: xzb = hn @ in_w[l]  (bf16 out; 32x64=2048 waves)
        gemm_bf16_direct<4><<<dim3(2048 / 64, NTOK / 64), wblk, 0, stream>>>(
            hn_bf, D_MODEL, iwt, D_MODEL, nullptr, xzb, 2048, nullptr,
            NTOK, 2048, D_MODEL, 8);

        // conv + silu: xzb[:, :1024] -> xb (bf16 u)
        conv_silu_kernel<<<dim3((NTOK * D_INNER) / 256), blk, 0, stream>>>(
            xzb, cw, cb, xb);

        // merged xproj+dt GEMM: dbl[:, :1024]=softplus(u@Wdt+dt_b),
        //                       dbl[:, 1024:1056]=B|C   (fp32 out; 18x64=1152 waves)
        gemm_bf16_direct<4><<<dim3(NCAT / 64, NTOK / 64), wblk, 0, stream>>>(
            xb, D_INNER, wc, D_INNER, dbl, nullptr, NCAT, db,
            NTOK, NCAT, D_INNER, 4);

        // chunked scan; pass3 overwrites xb in place with y*silu(z)
        scan_pass1<<<dim3(BATCH * PCH * (D_INNER / 256)), blk, 0, stream>>>(
            dbl, xb, al, hfin, sumdt);
        scan_pass2<<<dim3(BATCH * D_STATE * (D_INNER / 256)), blk, 0, stream>>>(
            al, sumdt, hfin);
        scan_pass3<<<dim3(BATCH * PCH * (D_INNER / 256)), blk, 0, stream>>>(
            dbl, xzb, al, dp, hfin, xb);

        // h += y_bf @ out_wt^T  (fp32 accumulate; 32-row waves, 8x128=1024)
        gemm_bf16_direct<2><<<dim3(D_MODEL / 64, NTOK / 32), wblk, 0, stream>>>(
            xb, D_INNER, owt, D_INNER, h, nullptr, D_MODEL, nullptr,
            NTOK, D_MODEL, D_INNER, 2);
    }

    // h -> bf16, lin2 (logits into dbl), softmax
    cast_bf16_kernel<<<dim3((NTOK * D_MODEL) / 256), blk, 0, stream>>>(h, xb);
    gemm_bf16_direct<4><<<dim3(LATENT / 64, NTOK / 64), wblk, 0, stream>>>(
        xb, D_MODEL, lin2_wt, D_MODEL, dbl, nullptr, LATENT, lin2_b,
        NTOK, LATENT, D_MODEL, 1);
    softmax_kernel<<<dim3((NTOK * LATENT) / 256), blk, 0, stream>>>(dbl, outp);
}

// Round 6
// 892.328 us; speedup vs baseline: 1.2069x; 1.2069x over previous
//
#include <hip/hip_runtime.h>
#include <math.h>

#define D_MODEL 512
#define N_LAYERS 4
#define LATENT 1024
#define D_INNER 1024
#define D_STATE 16
#define DT_RANK 32
#define KCONV 4
#define BATCH 4
#define SEQ 1024
#define NTOK (BATCH * SEQ) /* 4096 */
#define PCH 32
#define CLEN 32
#define NCAT 1152  /* merged xproj+dt GEMM N: 1024 dt | 32 B/C | 96 pad */

typedef __attribute__((ext_vector_type(8))) short short8;
typedef __attribute__((ext_vector_type(4))) float floatx4;
typedef unsigned short ushort_t;

// gfx9 s_waitcnt immediates: vmcnt lo[3:0] hi[15:14], expcnt[6:4], lgkm[11:8]
#define WC_VM4   0x0F74  /* vmcnt(4) */
#define WC_VM8   0x0F78  /* vmcnt(8) */
#define WC_VM0   0x0F70  /* vmcnt(0) */
#define WC_LGKM0 0xC07F  /* lgkmcnt(0), vm/exp free */

__device__ __forceinline__ ushort_t f2bf(float f) {
    union { float f; unsigned u; } v; v.f = f;
    unsigned r = v.u + 0x7FFFu + ((v.u >> 16) & 1u);  // RNE
    return (ushort_t)(r >> 16);
}
__device__ __forceinline__ float bf2f(ushort_t u) {
    union { unsigned u; float f; } v; v.u = ((unsigned)u) << 16;
    return v.f;
}
// async global -> LDS, 16B per lane (verified width=16 on gfx950, m97).
__device__ __forceinline__ void gll16(const void* g, void* l) {
    __builtin_amdgcn_global_load_lds(
        (const __attribute__((address_space(1))) void*)g,
        (__attribute__((address_space(3))) void*)l, 16, 0, 0);
}

// ---------------------------------------------------------------------------
// ROUND-6 MODEL (fits r0-r5): GEMM time ~= bytes staged into CUs / ~10B/cyc/CU.
// 64^2 tiles stage M*N*K*2*(2/64); the ONLY lever left is reuse.
// This kernel: 128x128 tile -> staged bytes x0.5 vs 64^2.
//   - 4 waves (2x2 wave grid); per-wave 64x64 via 4x4 16x16x32 frags
//     (exact per-wave layout of the r4 kernel, correctness-proven).
//   - staging/XOR-8 swizzle/2-buffer two-barrier loop = r0/r3-proven scheme,
//     8 gll16 per thread per tile, counted vmcnt(8).
//   - LDS 64 KB -> 2 blocks/CU; launch_bounds(256,2) (VGPR ~170 < 256).
//   - XCD-chunked bijective remap (r3: FETCH 37.6->18 MB) retained.
// flags: 1 = add bias[n], 2 = accumulate into C, 4 = softplus(v+bias) n<1024,
//        8 = bf16 out to Cb.
// ---------------------------------------------------------------------------
__global__ __launch_bounds__(256, 2) void gemm_bf16_t128(
    const ushort_t* __restrict__ A, int lda,
    const ushort_t* __restrict__ Bt, int ldb,
    float* __restrict__ C, ushort_t* __restrict__ Cb, int ldc,
    const float* __restrict__ bias,
    int M, int N, int K, int flags)
{
    __shared__ ushort_t As[2][8192];   // 2 x 16 KB: 128 rows x 64 cols
    __shared__ ushort_t Bs[2][8192];

    // XCD-chunked bijective remap (grids here have nwg % 8 == 0).
    const int gx = gridDim.x;
    const int nwg = gx * gridDim.y;
    const int orig = blockIdx.y * gx + blockIdx.x;
    const int qq = nwg >> 3, rr = nwg & 7;
    const int xcd = orig & 7, loc = orig >> 3;
    const int swz = (xcd < rr ? xcd * (qq + 1) : rr * (qq + 1) + (xcd - rr) * qq) + loc;
    const int m0 = (swz / gx) * 128;
    const int n0 = (swz % gx) * 128;

    const int tid = threadIdx.x;
    const int w = tid >> 6;
    const int lane = tid & 63;
    const int quad = lane >> 4;
    const int l16 = lane & 15;
    const int wm = (w & 1) * 64;
    const int wn = (w >> 1) * 64;

    // staging: thread -> slab row (tid>>3) (0..31), LDS chunk (tid&7);
    // fetches global chunk (tid&7)^(row&7). 4 slabs of 32 rows per matrix.
    const int srow = tid >> 3;
    const int schunk = ((tid & 7) ^ (srow & 7)) * 8;
    const ushort_t* ga = A + (size_t)(m0 + srow) * lda + schunk;
    const ushort_t* gb = Bt + (size_t)(n0 + srow) * ldb + schunk;
    const int lofs = tid * 8;  // linear DMA dest: slab base + lane*16B

    // read-side swizzle: frag row r -> r&7 = l16&7; global chunk (ks*4+quad)
    // lives at LDS chunk (ks*4+quad)^(l16&7).
    const int swz0 = ((0 * 4 + quad) ^ (l16 & 7)) * 8;
    const int swz1 = ((1 * 4 + quad) ^ (l16 & 7)) * 8;

    floatx4 acc[4][4] = {};
    const int nt = K >> 6;

    // 8 VMEM ops per thread per tile (4 A-slabs + 4 B-slabs).
    #define STAGE(t, b)                                                        \
        do {                                                                   \
            const ushort_t* pa_ = ga + (t) * 64;                               \
            const ushort_t* pb_ = gb + (t) * 64;                               \
            _Pragma("unroll")                                                  \
            for (int q = 0; q < 4; q++) {                                      \
                gll16(pa_ + (size_t)(q * 32) * lda, &As[(b)][q * 2048 + lofs]);\
                gll16(pb_ + (size_t)(q * 32) * ldb, &Bs[(b)][q * 2048 + lofs]);\
            }                                                                  \
        } while (0)

    STAGE(0, 0);

    for (int kt = 0; kt < nt; kt++) {
        const int cur = kt & 1;
        if (kt + 1 < nt) {
            STAGE(kt + 1, 1 - cur);                 // 8 newer in flight
            __builtin_amdgcn_s_waitcnt(WC_VM8);     // tile kt landed
        } else {
            __builtin_amdgcn_s_waitcnt(WC_VM0);
        }
        __builtin_amdgcn_s_barrier();
        __builtin_amdgcn_sched_barrier(0);  // no LDS read above this point

        short8 af[2][4], bfr[2][4];
        #pragma unroll
        for (int i = 0; i < 4; i++) {
            const int r = wm + i * 16 + l16;
            af[0][i] = *(const short8*)&As[cur][r * 64 + swz0];
            af[1][i] = *(const short8*)&As[cur][r * 64 + swz1];
        }
        #pragma unroll
        for (int j = 0; j < 4; j++) {
            const int r = wn + j * 16 + l16;
            bfr[0][j] = *(const short8*)&Bs[cur][r * 64 + swz0];
            bfr[1][j] = *(const short8*)&Bs[cur][r * 64 + swz1];
        }
        __builtin_amdgcn_s_waitcnt(WC_LGKM0);   // my ds_reads complete
        __builtin_amdgcn_s_barrier();           // all reads done -> buf reusable
        __builtin_amdgcn_sched_barrier(0);      // MFMAs stay below

        #pragma unroll
        for (int ks = 0; ks < 2; ks++)
            #pragma unroll
            for (int i = 0; i < 4; i++)
                #pragma unroll
                for (int j = 0; j < 4; j++)
                    acc[i][j] = __builtin_amdgcn_mfma_f32_16x16x32_bf16(
                        af[ks][i], bfr[ks][j], acc[i][j], 0, 0, 0);
    }
    #undef STAGE

    // C/D layout (m89-verified): col = lane&15, row = quad*4 + reg.
    #pragma unroll
    for (int j = 0; j < 4; j++) {
        int n = n0 + wn + j * 16 + l16;
        float bv = (flags & 1) ? bias[n] : 0.f;
        bool do_sp = (flags & 4) && (n < 1024);
        float spb = do_sp ? bias[n] : 0.f;
        #pragma unroll
        for (int i = 0; i < 4; i++) {
            int mrow = m0 + wm + i * 16 + quad * 4;
            #pragma unroll
            for (int rr2 = 0; rr2 < 4; rr2++) {
                size_t idx = (size_t)(mrow + rr2) * ldc + n;
                float v = acc[i][j][rr2] + bv;
                if (do_sp) {
                    v += spb;
                    v = (v > 20.f) ? v : log1pf(__expf(v));
                }
                if (flags & 8) {
                    Cb[idx] = f2bf(v);
                } else {
                    if (flags & 2) v += C[idx];
                    C[idx] = v;
                }
            }
        }
    }
}

// ---------------------------------------------------------------------------
// 64x64 fallback tile (r3 kernel VERBATIM — proven 43.6-44 us, passed):
// triple-buffered, distance-2 prefetch, single barrier, XOR-8 swizzle,
// XCD remap. Used for N=512 GEMMs (grid uniformity) and xproj's B/C slice.
// ---------------------------------------------------------------------------
__global__ __launch_bounds__(256, 3) void gemm_bf16_tile(
    const ushort_t* __restrict__ A, int lda,
    const ushort_t* __restrict__ Bt, int ldb,
    float* __restrict__ C, ushort_t* __restrict__ Cb, int ldc,
    const float* __restrict__ bias,
    int M, int N, int K, int flags)
{
    __shared__ ushort_t As[3][4096];   // 3 x 8 KB
    __shared__ ushort_t Bs[3][4096];   // 3 x 8 KB

    const int gx = gridDim.x;
    const int nwg = gx * gridDim.y;
    const int orig = blockIdx.y * gx + blockIdx.x;
    const int qq = nwg >> 3, rr = nwg & 7;
    const int xcd = orig & 7, loc = orig >> 3;
    const int swz = (xcd < rr ? xcd * (qq + 1) : rr * (qq + 1) + (xcd - rr) * qq) + loc;
    const int m0 = (swz / gx) * 64;
    const int n0 = (swz % gx) * 64;

    const int tid = threadIdx.x;
    const int w = tid >> 6;
    const int lane = tid & 63;
    const int quad = lane >> 4;
    const int l16 = lane & 15;
    const int wm = (w & 1) * 32;
    const int wn = (w >> 1) * 32;

    const int srow = tid >> 3;
    const int schunk = ((tid & 7) ^ (srow & 7)) * 8;
    const ushort_t* ga = A + (size_t)(m0 + srow) * lda + schunk;
    const ushort_t* gb = Bt + (size_t)(n0 + srow) * ldb + schunk;
    const int lofs = tid * 8;

    const int swz0 = ((0 * 4 + quad) ^ (l16 & 7)) * 8;
    const int swz1 = ((1 * 4 + quad) ^ (l16 & 7)) * 8;

    floatx4 acc[2][2] = {};
    const int nt = K >> 6;

    #define STAGE(t, b)                                         \
        do {                                                    \
            const ushort_t* pa_ = ga + (t) * 64;                \
            const ushort_t* pb_ = gb + (t) * 64;                \
            gll16(pa_, &As[(b)][lofs]);                         \
            gll16(pa_ + (size_t)32 * lda, &As[(b)][2048 + lofs]); \
            gll16(pb_, &Bs[(b)][lofs]);                         \
            gll16(pb_ + (size_t)32 * ldb, &Bs[(b)][2048 + lofs]); \
        } while (0)

    STAGE(0, 0);
    if (nt > 1) STAGE(1, 1);

    int cur = 0;
    for (int kt = 0; kt < nt; kt++) {
        if (kt + 1 < nt) __builtin_amdgcn_s_waitcnt(WC_VM4);
        else             __builtin_amdgcn_s_waitcnt(WC_VM0);
        __builtin_amdgcn_s_barrier();
        __builtin_amdgcn_sched_barrier(0);

        if (kt + 2 < nt) {
            int nb = cur + 2; if (nb >= 3) nb -= 3;
            STAGE(kt + 2, nb);
        }

        short8 af[2][2], bfr[2][2];
        #pragma unroll
        for (int i = 0; i < 2; i++) {
            const int r = wm + i * 16 + l16;
            af[0][i] = *(const short8*)&As[cur][r * 64 + swz0];
            af[1][i] = *(const short8*)&As[cur][r * 64 + swz1];
        }
        #pragma unroll
        for (int j = 0; j < 2; j++) {
            const int r = wn + j * 16 + l16;
            bfr[0][j] = *(const short8*)&Bs[cur][r * 64 + swz0];
            bfr[1][j] = *(const short8*)&Bs[cur][r * 64 + swz1];
        }
        __builtin_amdgcn_s_waitcnt(WC_LGKM0);
        __builtin_amdgcn_sched_barrier(0);

        #pragma unroll
        for (int ks = 0; ks < 2; ks++)
            #pragma unroll
            for (int i = 0; i < 2; i++)
                #pragma unroll
                for (int j = 0; j < 2; j++)
                    acc[i][j] = __builtin_amdgcn_mfma_f32_16x16x32_bf16(
                        af[ks][i], bfr[ks][j], acc[i][j], 0, 0, 0);

        cur++; if (cur == 3) cur = 0;
    }
    #undef STAGE

    #pragma unroll
    for (int j = 0; j < 2; j++) {
        int n = n0 + wn + j * 16 + l16;
        float bv = (flags & 1) ? bias[n] : 0.f;
        bool do_sp = (flags & 4) && (n < 1024);
        float spb = do_sp ? bias[n] : 0.f;
        #pragma unroll
        for (int i = 0; i < 2; i++) {
            int mrow = m0 + wm + i * 16 + quad * 4;
            #pragma unroll
            for (int rr2 = 0; rr2 < 4; rr2++) {
                size_t idx = (size_t)(mrow + rr2) * ldc + n;
                float v = acc[i][j][rr2] + bv;
                if (do_sp) {
                    v += spb;
                    v = (v > 20.f) ? v : log1pf(__expf(v));
                }
                if (flags & 8) {
                    Cb[idx] = f2bf(v);
                } else {
                    if (flags & 2) v += C[idx];
                    C[idx] = v;
                }
            }
        }
    }
}

// ---------------------------------------------------------------------------
// build_wdt: Wcat rows 0..1023 = (xw[:, :32] @ dt_w)^T, bf16 [n][k].
// ---------------------------------------------------------------------------
__global__ __launch_bounds__(256) void build_wdt_kernel(
    const float* __restrict__ xproj_w, const float* __restrict__ dt_w,
    ushort_t* __restrict__ wcat)
{
    const int l = blockIdx.z;
    const int n0 = blockIdx.x * 64;
    const int k0 = blockIdx.y * 64;
    const float* xw  = xproj_w + (size_t)l * D_INNER * 64;
    const float* dtw = dt_w + (size_t)l * DT_RANK * D_INNER;

    __shared__ float xs[64][33];   // [k][r]
    __shared__ float ds[32][65];   // [r][n]

    const int tid = threadIdx.x;
    {
        int row = tid >> 2;
        int col = (tid & 3) * 8;
        #pragma unroll
        for (int q = 0; q < 8; q++)
            xs[row][col + q] = xw[(size_t)(k0 + row) * 64 + col + q];
    }
    {
        int row = tid >> 3;
        int col = (tid & 7) * 8;
        #pragma unroll
        for (int q = 0; q < 8; q++)
            ds[row][col + q] = dtw[(size_t)row * D_INNER + n0 + col + q];
    }
    __syncthreads();

    const int ty = tid & 15;
    const int tx = tid >> 4;
    float acc[4][4] = {};
    #pragma unroll
    for (int r = 0; r < 32; r++) {
        float a[4], b[4];
        #pragma unroll
        for (int i = 0; i < 4; i++) a[i] = xs[ty * 4 + i][r];
        #pragma unroll
        for (int j = 0; j < 4; j++) b[j] = ds[r][tx * 4 + j];
        #pragma unroll
        for (int j = 0; j < 4; j++)
            #pragma unroll
            for (int i = 0; i < 4; i++)
                acc[j][i] = fmaf(a[i], b[j], acc[j][i]);
    }
    #pragma unroll
    for (int j = 0; j < 4; j++) {
        int n = n0 + tx * 4 + j;
        ushort4 o;
        o.x = f2bf(acc[j][0]); o.y = f2bf(acc[j][1]);
        o.z = f2bf(acc[j][2]); o.w = f2bf(acc[j][3]);
        *(ushort4*)&wcat[((size_t)l * NCAT + n) * D_INNER + k0 + ty * 4] = o;
    }
}

// ---------------------------------------------------------------------------
// build_wbc: Wcat rows 1024..1151: j<32 -> xw[k][32+j] cast; else zero pad.
// (Pad MUST be written every launch: d_ws is re-poisoned to 0xAA.)
// ---------------------------------------------------------------------------
__global__ __launch_bounds__(256) void build_wbc_kernel(
    const float* __restrict__ xproj_w, ushort_t* __restrict__ wcat)
{
    const int idx = blockIdx.x * 256 + threadIdx.x;
    const int k = idx & 1023;
    const int j = (idx >> 10) & 127;
    const int l = idx >> 17;
    ushort_t v = 0;
    if (j < 32)
        v = f2bf(xproj_w[((size_t)l * D_INNER + k) * 64 + 32 + j]);
    wcat[((size_t)l * NCAT + 1024 + j) * D_INNER + k] = v;
}

// ---------------------------------------------------------------------------
__global__ __launch_bounds__(256) void transpose_cast_kernel(
    const float* __restrict__ in, ushort_t* __restrict__ out, int K, int N)
{
    __shared__ float tile[32][33];
    const int n0 = blockIdx.x * 32, k0 = blockIdx.y * 32;
    const int tx = threadIdx.x & 31, ty = threadIdx.x >> 5;
    #pragma unroll
    for (int i = 0; i < 4; i++)
        tile[ty + i * 8][tx] = in[(size_t)(k0 + ty + i * 8) * N + n0 + tx];
    __syncthreads();
    #pragma unroll
    for (int i = 0; i < 4; i++)
        out[(size_t)(n0 + ty + i * 8) * K + k0 + tx] = f2bf(tile[tx][ty + i * 8]);
}

// ---------------------------------------------------------------------------
__global__ __launch_bounds__(256) void cast_bf16_kernel(
    const float* __restrict__ in, ushort_t* __restrict__ out)
{
    const int i = blockIdx.x * 256 + threadIdx.x;
    out[i] = f2bf(in[i]);
}

// ---------------------------------------------------------------------------
__global__ __launch_bounds__(256) void rmsnorm_kernel(
    const float* __restrict__ x, const float* __restrict__ w,
    ushort_t* __restrict__ y)
{
    const int row = blockIdx.x;
    const float* xr = x + (size_t)row * D_MODEL;
    ushort_t* yr = y + (size_t)row * D_MODEL;
    const int tid = threadIdx.x;

    float v0 = xr[tid], v1 = xr[tid + 256];
    float ss = v0 * v0 + v1 * v1;
    #pragma unroll
    for (int off = 32; off > 0; off >>= 1) ss += __shfl_down(ss, off);

    __shared__ float wsum[4];
    __shared__ float scale_s;
    int wid = tid >> 6, lane = tid & 63;
    if (lane == 0) wsum[wid] = ss;
    __syncthreads();
    if (tid == 0) {
        float tot = wsum[0] + wsum[1] + wsum[2] + wsum[3];
        scale_s = 1.0f / sqrtf(tot / (float)D_MODEL + 1e-5f);
    }
    __syncthreads();
    float sc = scale_s;
    yr[tid] = f2bf(v0 * sc * w[tid]);
    yr[tid + 256] = f2bf(v1 * sc * w[tid + 256]);
}

// ---------------------------------------------------------------------------
// Causal dwconv (K=4) + bias + silu. Reads bf16 xz (stride 2048, xp plane),
// writes bf16 u.
// ---------------------------------------------------------------------------
__global__ __launch_bounds__(256) void conv_silu_kernel(
    const ushort_t* __restrict__ xz, const float* __restrict__ w,
    const float* __restrict__ bconv, ushort_t* __restrict__ outb)
{
    const int idx = blockIdx.x * 256 + threadIdx.x;
    const int d = idx & (D_INNER - 1);
    const int t = (idx >> 10) & (SEQ - 1);
    const int row = idx >> 10;
    const ushort_t* base = xz + (size_t)row * 2048 + d;

    float s = 0.f;
    #pragma unroll
    for (int k = 0; k < KCONV; k++) {
        int tt = t + k - (KCONV - 1);
        if (tt >= 0)
            s = fmaf(bf2f(base[(ptrdiff_t)(k - (KCONV - 1)) * 2048]), w[d * KCONV + k], s);
    }
    s += bconv[d];
    float r = s / (1.f + __expf(-s));
    outb[idx] = f2bf(r);
}

// ---------------------------------------------------------------------------
// Chunked selective scan (3 passes), CLEN=32. dt/B/C in dbl (stride NCAT):
// dbl[row][d]=softplus'ed dt; dbl[row][1024+n]=B[n]; dbl[row][1040+n]=C[n].
// u is bf16 in xb; z is bf16 in xz[:,1024:].
// ---------------------------------------------------------------------------
__global__ __launch_bounds__(256) void scan_pass1(
    const float* __restrict__ dbl, const ushort_t* __restrict__ ub,
    const float* __restrict__ A_log,
    float* __restrict__ hfin, float* __restrict__ sumdt)
{
    const int tid = threadIdx.x;
    const int b = blockIdx.x >> 7;
    const int p = (blockIdx.x >> 2) & 31;
    const int d = ((blockIdx.x & 3) << 8) + tid;
    const int t0 = p * CLEN;

    float A[D_STATE];
    #pragma unroll
    for (int n = 0; n < D_STATE; n++) A[n] = -expf(A_log[d * D_STATE + n]);

    float h[D_STATE] = {};
    float sdt = 0.f;

    const float* dtp = dbl + ((size_t)b * SEQ + t0) * NCAT + d;
    const float* bp  = dbl + ((size_t)b * SEQ + t0) * NCAT + 1024;
    const ushort_t* up = ub + ((size_t)b * SEQ + t0) * D_INNER + d;

    for (int t = 0; t < CLEN; t++) {
        float dtv = dtp[(size_t)t * NCAT];
        float uv  = bf2f(up[(size_t)t * D_INNER]);
        float dtu = dtv * uv;
        sdt += dtv;
        #pragma unroll
        for (int n = 0; n < D_STATE; n++)
            h[n] = fmaf(__expf(dtv * A[n]), h[n], dtu * bp[t * NCAT + n]);
    }

    size_t base = (size_t)(b * PCH + p) * D_STATE * D_INNER + d;
    #pragma unroll
    for (int n = 0; n < D_STATE; n++) hfin[base + (size_t)n * D_INNER] = h[n];
    sumdt[(size_t)(b * PCH + p) * D_INNER + d] = sdt;
}

__global__ __launch_bounds__(256) void scan_pass2(
    const float* __restrict__ A_log, const float* __restrict__ sumdt,
    float* __restrict__ hc)
{
    const int tid = threadIdx.x;
    const int b = blockIdx.x >> 6;
    const int n = (blockIdx.x >> 2) & 15;
    const int d = ((blockIdx.x & 3) << 8) + tid;

    const float Aval = -expf(A_log[d * D_STATE + n]);
    float h = 0.f;
    for (int p = 0; p < PCH; p++) {
        size_t idx = ((size_t)(b * PCH + p) * D_STATE + n) * D_INNER + d;
        float fin = hc[idx];
        hc[idx] = h;
        h = fmaf(__expf(Aval * sumdt[(size_t)(b * PCH + p) * D_INNER + d]), h, fin);
    }
}

// pass3: u (bf16, in ub) read then overwritten IN PLACE with y*silu(z).
__global__ __launch_bounds__(256) void scan_pass3(
    const float* __restrict__ dbl, const ushort_t* __restrict__ xz,
    const float* __restrict__ A_log, const float* __restrict__ Dp,
    const float* __restrict__ hstart, ushort_t* ub)
{
    const int tid = threadIdx.x;
    const int b = blockIdx.x >> 7;
    const int p = (blockIdx.x >> 2) & 31;
    const int d = ((blockIdx.x & 3) << 8) + tid;
    const int t0 = p * CLEN;

    float A[D_STATE];
    #pragma unroll
    for (int n = 0; n < D_STATE; n++) A[n] = -expf(A_log[d * D_STATE + n]);
    const float Dv = Dp[d];

    float h[D_STATE];
    size_t base = (size_t)(b * PCH + p) * D_STATE * D_INNER + d;
    #pragma unroll
    for (int n = 0; n < D_STATE; n++) h[n] = hstart[base + (size_t)n * D_INNER];

    const float* dtp = dbl + ((size_t)b * SEQ + t0) * NCAT + d;
    const float* bp  = dbl + ((size_t)b * SEQ + t0) * NCAT + 1024;
    const ushort_t* zp = xz + ((size_t)b * SEQ + t0) * 2048 + 1024 + d;
    ushort_t* up = ub + ((size_t)b * SEQ + t0) * D_INNER + d;

    for (int t = 0; t < CLEN; t++) {
        float dtv = dtp[(size_t)t * NCAT];
        float uv  = bf2f(up[(size_t)t * D_INNER]);
        float zv  = bf2f(zp[(size_t)t * 2048]);
        float dtu = dtv * uv;
        float y = 0.f;
        #pragma unroll
        for (int n = 0; n < D_STATE; n++) {
            h[n] = fmaf(__expf(dtv * A[n]), h[n], dtu * bp[t * NCAT + n]);
            y = fmaf(h[n], bp[t * NCAT + 16 + n], y);
        }
        float res = fmaf(uv, Dv, y);
        res *= zv / (1.f + __expf(-zv));
        up[(size_t)t * D_INNER] = f2bf(res);
    }
}

// ---------------------------------------------------------------------------
__global__ __launch_bounds__(256) void softmax_kernel(
    const float* __restrict__ in, float* __restrict__ out)
{
    const int idx = blockIdx.x * 256 + threadIdx.x;
    float v = in[idx];
    float m = v;
    #pragma unroll
    for (int off = 16; off > 0; off >>= 1) m = fmaxf(m, __shfl_xor(m, off, 32));
    float e = expf(v - m);
    float s = e;
    #pragma unroll
    for (int off = 16; off > 0; off >>= 1) s += __shfl_xor(s, off, 32);
    out[idx] = e / s;
}

// ---------------------------------------------------------------------------
extern "C" void kernel_launch(void* const* d_in, const int* in_sizes, int n_in,
                              void* d_out, int out_size, void* d_ws, size_t ws_size,
                              hipStream_t stream)
{
    const float* x       = (const float*)d_in[0];
    const float* lin1_w  = (const float*)d_in[1];
    const float* lin1_b  = (const float*)d_in[2];
    const float* norm_w  = (const float*)d_in[3];
    const float* in_w    = (const float*)d_in[4];
    const float* conv_w  = (const float*)d_in[5];
    const float* conv_b  = (const float*)d_in[6];
    const float* xproj_w = (const float*)d_in[7];
    const float* dt_w    = (const float*)d_in[8];
    const float* dt_b    = (const float*)d_in[9];
    const float* A_log   = (const float*)d_in[10];
    const float* Dp      = (const float*)d_in[11];
    const float* out_w   = (const float*)d_in[12];
    const float* lin2_w  = (const float*)d_in[13];
    const float* lin2_b  = (const float*)d_in[14];
    float* outp = (float*)d_out;
    (void)ws_size; (void)in_sizes; (void)n_in; (void)out_size;

    float* ws = (float*)d_ws;
    const size_t F1M = 1u << 20;
    float* h     = ws;                        // 2M fl
    float* dbl   = h + 2 * F1M;               // 4.5M fl (also lin2 logits)
    float* sumdt = dbl + (size_t)NTOK * NCAT; // 128K fl
    float* hfin  = sumdt + (size_t)BATCH * PCH * D_INNER; // 2M fl
    ushort_t* xzb   = (ushort_t*)(hfin + 2 * F1M);        // 8M us (xp|z, 2048)
    ushort_t* hn_bf = xzb + 8 * F1M;                      // 2M us
    ushort_t* xb    = hn_bf + 2 * F1M;                    // 4M us
    ushort_t* lin1_wt = xb + 4 * F1M;                     // 512*1024
    ushort_t* in_wt   = lin1_wt + (size_t)512 * 1024;     // 4*2048*512
    ushort_t* out_wt  = in_wt + (size_t)4 * 2048 * 512;   // 4*512*1024
    ushort_t* lin2_wt = out_wt + (size_t)4 * 512 * 1024;  // 1024*512
    ushort_t* wcat    = lin2_wt + (size_t)1024 * 512;     // 4*1152*1024

    dim3 blk(256);

    // --- weight prep ---
    transpose_cast_kernel<<<dim3(512 / 32, 1024 / 32), blk, 0, stream>>>(
        lin1_w, lin1_wt, LATENT, D_MODEL);
    for (int l = 0; l < N_LAYERS; l++) {
        transpose_cast_kernel<<<dim3(2048 / 32, 512 / 32), blk, 0, stream>>>(
            in_w + (size_t)l * 512 * 2048, in_wt + (size_t)l * 2048 * 512, 512, 2048);
        transpose_cast_kernel<<<dim3(512 / 32, 1024 / 32), blk, 0, stream>>>(
            out_w + (size_t)l * 1024 * 512, out_wt + (size_t)l * 512 * 1024, 1024, 512);
    }
    transpose_cast_kernel<<<dim3(1024 / 32, 512 / 32), blk, 0, stream>>>(
        lin2_w, lin2_wt, D_MODEL, LATENT);
    build_wdt_kernel<<<dim3(16, 16, N_LAYERS), blk, 0, stream>>>(
        xproj_w, dt_w, wcat);
    build_wbc_kernel<<<dim3((N_LAYERS * 128 * 1024) / 256), blk, 0, stream>>>(
        xproj_w, wcat);

    // x -> bf16
    cast_bf16_kernel<<<dim3((NTOK * LATENT) / 256), blk, 0, stream>>>(x, xb);

    // lin1: h = x_bf @ lin1_wt^T + b  (fp32 out; 64^2, 8x64=512 blocks)
    gemm_bf16_tile<<<dim3(D_MODEL / 64, NTOK / 64), blk, 0, stream>>>(
        xb, LATENT, lin1_wt, LATENT, h, nullptr, D_MODEL, lin1_b,
        NTOK, D_MODEL, LATENT, 1);

    for (int l = 0; l < N_LAYERS; l++) {
        const float* nw = norm_w + (size_t)l * D_MODEL;
        const float* cw = conv_w + (size_t)l * D_INNER * KCONV;
        const float* cb = conv_b + (size_t)l * D_INNER;
        const float* db = dt_b + (size_t)l * D_INNER;
        const float* al = A_log + (size_t)l * D_INNER * D_STATE;
        const float* dp = Dp + (size_t)l * D_INNER;
        const ushort_t* iwt = in_wt + (size_t)l * 2048 * 512;
        const ushort_t* owt = out_wt + (size_t)l * 512 * 1024;
        const ushort_t* wc  = wcat + (size_t)l * NCAT * D_INNER;

        rmsnorm_kernel<<<dim3(NTOK), blk, 0, stream>>>(h, nw, hn_bf);

        // fused in-proj: xzb = hn @ in_w[l] (bf16 out; 128^2, 16x32=512 blocks)
        gemm_bf16_t128<<<dim3(2048 / 128, NTOK / 128), blk, 0, stream>>>(
            hn_bf, D_MODEL, iwt, D_MODEL, nullptr, xzb, 2048, nullptr,
            NTOK, 2048, D_MODEL, 8);

        // conv + silu: xzb[:, :1024] -> xb (bf16 u)
        conv_silu_kernel<<<dim3((NTOK * D_INNER) / 256), blk, 0, stream>>>(
            xzb, cw, cb, xb);

        // xproj-dt (N=1024): dbl[:, :1024] = softplus(u@Wdt + dt_b)
        // (128^2, 8x32=256 blocks; halves staged bytes vs 64^2)
        gemm_bf16_t128<<<dim3(1024 / 128, NTOK / 128), blk, 0, stream>>>(
            xb, D_INNER, wc, D_INNER, dbl, nullptr, NCAT, db,
            NTOK, 1024, D_INNER, 4);

        // xproj-BC (cols 1024..1087: 32 B/C + 32 zero-pad rows of wcat):
        // raw values, no bias/softplus (flags 0); 64^2, 1x64=64 blocks.
        gemm_bf16_tile<<<dim3(1, NTOK / 64), blk, 0, stream>>>(
            xb, D_INNER, wc + (size_t)1024 * D_INNER, D_INNER,
            dbl + 1024, nullptr, NCAT, db,
            NTOK, 64, D_INNER, 0);

        // chunked scan; pass3 overwrites xb in place with y*silu(z)
        scan_pass1<<<dim3(BATCH * PCH * (D_INNER / 256)), blk, 0, stream>>>(
            dbl, xb, al, hfin, sumdt);
        scan_pass2<<<dim3(BATCH * D_STATE * (D_INNER / 256)), blk, 0, stream>>>(
            al, sumdt, hfin);
        scan_pass3<<<dim3(BATCH * PCH * (D_INNER / 256)), blk, 0, stream>>>(
            dbl, xzb, al, dp, hfin, xb);

        // h += y_bf @ out_wt^T  (fp32 accumulate; 64^2, 8x64=512 blocks)
        gemm_bf16_tile<<<dim3(D_MODEL / 64, NTOK / 64), blk, 0, stream>>>(
            xb, D_INNER, owt, D_INNER, h, nullptr, D_MODEL, nullptr,
            NTOK, D_MODEL, D_INNER, 2);
    }

    // h -> bf16, lin2 (logits into dbl; 128^2, 8x32=256 blocks), softmax
    cast_bf16_kernel<<<dim3((NTOK * D_MODEL) / 256), blk, 0, stream>>>(h, xb);
    gemm_bf16_t128<<<dim3(LATENT / 128, NTOK / 128), blk, 0, stream>>>(
        xb, D_MODEL, lin2_wt, D_MODEL, dbl, nullptr, LATENT, lin2_b,
        NTOK, LATENT, D_MODEL, 1);
    softmax_kernel<<<dim3((NTOK * LATENT) / 256), blk, 0, stream>>>(dbl, outp);
}

// Round 8
// 756.788 us; speedup vs baseline: 1.4230x; 1.1791x over previous
//
#include <hip/hip_runtime.h>
#include <math.h>

#define D_MODEL 512
#define N_LAYERS 4
#define LATENT 1024
#define D_INNER 1024
#define D_STATE 16
#define DT_RANK 32
#define KCONV 4
#define BATCH 4
#define SEQ 1024
#define NTOK (BATCH * SEQ) /* 4096 */
#define PCH 32
#define CLEN 32

typedef __attribute__((ext_vector_type(8))) short short8;
typedef __attribute__((ext_vector_type(4))) float floatx4;
typedef unsigned short ushort_t;

// gfx9 s_waitcnt immediates: vmcnt lo[3:0] hi[15:14], expcnt[6:4], lgkm[11:8]
#define WC_VM4   0x0F74  /* vmcnt(4) */
#define WC_VM0   0x0F70  /* vmcnt(0) */
#define WC_LGKM0 0xC07F  /* lgkmcnt(0), vm/exp free */

__device__ __forceinline__ ushort_t f2bf(float f) {
    union { float f; unsigned u; } v; v.f = f;
    unsigned r = v.u + 0x7FFFu + ((v.u >> 16) & 1u);  // RNE
    return (ushort_t)(r >> 16);
}
__device__ __forceinline__ float bf2f(ushort_t u) {
    union { unsigned u; float f; } v; v.u = ((unsigned)u) << 16;
    return v.f;
}
// async global -> LDS, 16B per lane (verified width=16 on gfx950, m97).
__device__ __forceinline__ void gll16(const void* g, void* l) {
    __builtin_amdgcn_global_load_lds(
        (const __attribute__((address_space(1))) void*)g,
        (__attribute__((address_space(3))) void*)l, 16, 0, 0);
}

// ---------------------------------------------------------------------------
// bf16 MFMA GEMM, 64x64 tile (r3 structure VERBATIM — proven 43.6-44 us):
// triple-buffered LDS, distance-2 prefetch, single barrier per iter, XOR-8
// swizzle (conflicts=0), XCD-chunked bijective remap (FETCH 37.6->18MB).
// Rate-optimization abandoned after 6 null rounds (every multi-wave
// structure ~200 TF at these shapes, matching m102's curve). Round 7/8
// cuts FLOPs instead: the rank-32 dt path is factorized (see launcher),
// supported via flag 16.
// flags: 1 = add bias[n], 2 = accumulate into C (fp32),
//        4 = softplus(v + bias[n]) for n<1024,
//        8 = write bf16 to Cb only,
//       16 = write fp32 to C AND bf16 to Cb (low-rank intermediate).
// ---------------------------------------------------------------------------
__global__ __launch_bounds__(256, 3) void gemm_bf16_tile(
    const ushort_t* __restrict__ A, int lda,
    const ushort_t* __restrict__ Bt, int ldb,
    float* __restrict__ C, ushort_t* __restrict__ Cb, int ldc,
    const float* __restrict__ bias,
    int M, int N, int K, int flags)
{
    __shared__ ushort_t As[3][4096];   // 3 x 8 KB
    __shared__ ushort_t Bs[3][4096];   // 3 x 8 KB

    const int gx = gridDim.x;
    const int nwg = gx * gridDim.y;
    const int orig = blockIdx.y * gx + blockIdx.x;
    const int qq = nwg >> 3, rr = nwg & 7;
    const int xcd = orig & 7, loc = orig >> 3;
    const int swz = (xcd < rr ? xcd * (qq + 1) : rr * (qq + 1) + (xcd - rr) * qq) + loc;
    const int m0 = (swz / gx) * 64;
    const int n0 = (swz % gx) * 64;

    const int tid = threadIdx.x;
    const int w = tid >> 6;
    const int lane = tid & 63;
    const int quad = lane >> 4;
    const int l16 = lane & 15;
    const int wm = (w & 1) * 32;
    const int wn = (w >> 1) * 32;

    const int srow = tid >> 3;
    const int schunk = ((tid & 7) ^ (srow & 7)) * 8;
    const ushort_t* ga = A + (size_t)(m0 + srow) * lda + schunk;
    const ushort_t* gb = Bt + (size_t)(n0 + srow) * ldb + schunk;
    const int lofs = tid * 8;

    const int swz0 = ((0 * 4 + quad) ^ (l16 & 7)) * 8;
    const int swz1 = ((1 * 4 + quad) ^ (l16 & 7)) * 8;

    floatx4 acc[2][2] = {};
    const int nt = K >> 6;

    #define STAGE(t, b)                                         \
        do {                                                    \
            const ushort_t* pa_ = ga + (t) * 64;                \
            const ushort_t* pb_ = gb + (t) * 64;                \
            gll16(pa_, &As[(b)][lofs]);                         \
            gll16(pa_ + (size_t)32 * lda, &As[(b)][2048 + lofs]); \
            gll16(pb_, &Bs[(b)][lofs]);                         \
            gll16(pb_ + (size_t)32 * ldb, &Bs[(b)][2048 + lofs]); \
        } while (0)

    STAGE(0, 0);
    if (nt > 1) STAGE(1, 1);

    int cur = 0;
    for (int kt = 0; kt < nt; kt++) {
        if (kt + 1 < nt) __builtin_amdgcn_s_waitcnt(WC_VM4);
        else             __builtin_amdgcn_s_waitcnt(WC_VM0);
        __builtin_amdgcn_s_barrier();
        __builtin_amdgcn_sched_barrier(0);

        if (kt + 2 < nt) {
            int nb = cur + 2; if (nb >= 3) nb -= 3;
            STAGE(kt + 2, nb);
        }

        short8 af[2][2], bfr[2][2];
        #pragma unroll
        for (int i = 0; i < 2; i++) {
            const int r = wm + i * 16 + l16;
            af[0][i] = *(const short8*)&As[cur][r * 64 + swz0];
            af[1][i] = *(const short8*)&As[cur][r * 64 + swz1];
        }
        #pragma unroll
        for (int j = 0; j < 2; j++) {
            const int r = wn + j * 16 + l16;
            bfr[0][j] = *(const short8*)&Bs[cur][r * 64 + swz0];
            bfr[1][j] = *(const short8*)&Bs[cur][r * 64 + swz1];
        }
        __builtin_amdgcn_s_waitcnt(WC_LGKM0);
        __builtin_amdgcn_sched_barrier(0);

        #pragma unroll
        for (int ks = 0; ks < 2; ks++)
            #pragma unroll
            for (int i = 0; i < 2; i++)
                #pragma unroll
                for (int j = 0; j < 2; j++)
                    acc[i][j] = __builtin_amdgcn_mfma_f32_16x16x32_bf16(
                        af[ks][i], bfr[ks][j], acc[i][j], 0, 0, 0);

        cur++; if (cur == 3) cur = 0;
    }
    #undef STAGE

    // C/D layout (m89-verified): col = lane&15, row = quad*4 + reg.
    #pragma unroll
    for (int j = 0; j < 2; j++) {
        int n = n0 + wn + j * 16 + l16;
        float bv = (flags & 1) ? bias[n] : 0.f;
        bool do_sp = (flags & 4) && (n < 1024);
        float spb = do_sp ? bias[n] : 0.f;
        #pragma unroll
        for (int i = 0; i < 2; i++) {
            int mrow = m0 + wm + i * 16 + quad * 4;
            #pragma unroll
            for (int rr2 = 0; rr2 < 4; rr2++) {
                size_t idx = (size_t)(mrow + rr2) * ldc + n;
                float v = acc[i][j][rr2] + bv;
                if (do_sp) {
                    v += spb;
                    v = (v > 20.f) ? v : log1pf(__expf(v));
                }
                if (flags & 8) {
                    Cb[idx] = f2bf(v);
                } else {
                    if (flags & 2) v += C[idx];
                    C[idx] = v;
                    if (flags & 16) Cb[idx] = f2bf(v);
                }
            }
        }
    }
}

// ---------------------------------------------------------------------------
// build_w2t: W2t[l][n][k] = (k<32) ? bf16(dt_w[l][k][n]) : 0.
// Pads rank-32 dt_w to K=64 so the dt GEMM is exactly one K-tile; the
// zero rows null out the B/C columns of the low-rank intermediate.
// (Pad MUST be written every launch: d_ws is re-poisoned to 0xAA.)
// ---------------------------------------------------------------------------
__global__ __launch_bounds__(256) void build_w2t_kernel(
    const float* __restrict__ dt_w, ushort_t* __restrict__ w2t)
{
    const int idx = blockIdx.x * 256 + threadIdx.x;
    const int k = idx & 63;
    const int n = (idx >> 6) & 1023;
    const int l = idx >> 16;
    ushort_t v = 0;
    if (k < 32)
        v = f2bf(dt_w[((size_t)l * DT_RANK + k) * D_INNER + n]);
    w2t[((size_t)l * 1024 + n) * 64 + k] = v;
}

// ---------------------------------------------------------------------------
__global__ __launch_bounds__(256) void transpose_cast_kernel(
    const float* __restrict__ in, ushort_t* __restrict__ out, int K, int N)
{
    __shared__ float tile[32][33];
    const int n0 = blockIdx.x * 32, k0 = blockIdx.y * 32;
    const int tx = threadIdx.x & 31, ty = threadIdx.x >> 5;
    #pragma unroll
    for (int i = 0; i < 4; i++)
        tile[ty + i * 8][tx] = in[(size_t)(k0 + ty + i * 8) * N + n0 + tx];
    __syncthreads();
    #pragma unroll
    for (int i = 0; i < 4; i++)
        out[(size_t)(n0 + ty + i * 8) * K + k0 + tx] = f2bf(tile[tx][ty + i * 8]);
}

// ---------------------------------------------------------------------------
__global__ __launch_bounds__(256) void cast_bf16_kernel(
    const float* __restrict__ in, ushort_t* __restrict__ out)
{
    const int i = blockIdx.x * 256 + threadIdx.x;
    out[i] = f2bf(in[i]);
}

// ---------------------------------------------------------------------------
__global__ __launch_bounds__(256) void rmsnorm_kernel(
    const float* __restrict__ x, const float* __restrict__ w,
    ushort_t* __restrict__ y)
{
    const int row = blockIdx.x;
    const float* xr = x + (size_t)row * D_MODEL;
    ushort_t* yr = y + (size_t)row * D_MODEL;
    const int tid = threadIdx.x;

    float v0 = xr[tid], v1 = xr[tid + 256];
    float ss = v0 * v0 + v1 * v1;
    #pragma unroll
    for (int off = 32; off > 0; off >>= 1) ss += __shfl_down(ss, off);

    __shared__ float wsum[4];
    __shared__ float scale_s;
    int wid = tid >> 6, lane = tid & 63;
    if (lane == 0) wsum[wid] = ss;
    __syncthreads();
    if (tid == 0) {
        float tot = wsum[0] + wsum[1] + wsum[2] + wsum[3];
        scale_s = 1.0f / sqrtf(tot / (float)D_MODEL + 1e-5f);
    }
    __syncthreads();
    float sc = scale_s;
    yr[tid] = f2bf(v0 * sc * w[tid]);
    yr[tid + 256] = f2bf(v1 * sc * w[tid + 256]);
}

// ---------------------------------------------------------------------------
// Causal dwconv (K=4) + bias + silu. Reads bf16 xz (stride 2048, xp plane),
// writes bf16 u.
// ---------------------------------------------------------------------------
__global__ __launch_bounds__(256) void conv_silu_kernel(
    const ushort_t* __restrict__ xz, const float* __restrict__ w,
    const float* __restrict__ bconv, ushort_t* __restrict__ outb)
{
    const int idx = blockIdx.x * 256 + threadIdx.x;
    const int d = idx & (D_INNER - 1);
    const int t = (idx >> 10) & (SEQ - 1);
    const int row = idx >> 10;
    const ushort_t* base = xz + (size_t)row * 2048 + d;

    float s = 0.f;
    #pragma unroll
    for (int k = 0; k < KCONV; k++) {
        int tt = t + k - (KCONV - 1);
        if (tt >= 0)
            s = fmaf(bf2f(base[(ptrdiff_t)(k - (KCONV - 1)) * 2048]), w[d * KCONV + k], s);
    }
    s += bconv[d];
    float r = s / (1.f + __expf(-s));
    outb[idx] = f2bf(r);
}

// ---------------------------------------------------------------------------
// Chunked selective scan (3 passes), CLEN=32.
// dt in dtb (stride 1024, already softplus'ed); B/C in bc (stride 64):
// bc[row][32+n]=B[n], bc[row][48+n]=C[n]. u bf16 in ub; z bf16 in xz[:,1024:].
// ---------------------------------------------------------------------------
__global__ __launch_bounds__(256) void scan_pass1(
    const float* __restrict__ dtb, const float* __restrict__ bc,
    const ushort_t* __restrict__ ub, const float* __restrict__ A_log,
    float* __restrict__ hfin, float* __restrict__ sumdt)
{
    const int tid = threadIdx.x;
    const int b = blockIdx.x >> 7;
    const int p = (blockIdx.x >> 2) & 31;
    const int d = ((blockIdx.x & 3) << 8) + tid;
    const int t0 = p * CLEN;

    float A[D_STATE];
    #pragma unroll
    for (int n = 0; n < D_STATE; n++) A[n] = -expf(A_log[d * D_STATE + n]);

    float h[D_STATE] = {};
    float sdt = 0.f;

    const float* dtp = dtb + ((size_t)b * SEQ + t0) * 1024 + d;
    const float* bp  = bc + ((size_t)b * SEQ + t0) * 64 + 32;
    const ushort_t* up = ub + ((size_t)b * SEQ + t0) * D_INNER + d;

    for (int t = 0; t < CLEN; t++) {
        float dtv = dtp[(size_t)t * 1024];
        float uv  = bf2f(up[(size_t)t * D_INNER]);
        float dtu = dtv * uv;
        sdt += dtv;
        #pragma unroll
        for (int n = 0; n < D_STATE; n++)
            h[n] = fmaf(__expf(dtv * A[n]), h[n], dtu * bp[t * 64 + n]);
    }

    size_t base = (size_t)(b * PCH + p) * D_STATE * D_INNER + d;
    #pragma unroll
    for (int n = 0; n < D_STATE; n++) hfin[base + (size_t)n * D_INNER] = h[n];
    sumdt[(size_t)(b * PCH + p) * D_INNER + d] = sdt;
}

__global__ __launch_bounds__(256) void scan_pass2(
    const float* __restrict__ A_log, const float* __restrict__ sumdt,
    float* __restrict__ hc)
{
    const int tid = threadIdx.x;
    const int b = blockIdx.x >> 6;
    const int n = (blockIdx.x >> 2) & 15;
    const int d = ((blockIdx.x & 3) << 8) + tid;

    const float Aval = -expf(A_log[d * D_STATE + n]);
    float h = 0.f;
    for (int p = 0; p < PCH; p++) {
        size_t idx = ((size_t)(b * PCH + p) * D_STATE + n) * D_INNER + d;
        float fin = hc[idx];
        hc[idx] = h;
        h = fmaf(__expf(Aval * sumdt[(size_t)(b * PCH + p) * D_INNER + d]), h, fin);
    }
}

// pass3: u (bf16, in ub) read then overwritten IN PLACE with y*silu(z).
__global__ __launch_bounds__(256) void scan_pass3(
    const float* __restrict__ dtb, const float* __restrict__ bc,
    const ushort_t* __restrict__ xz, const float* __restrict__ A_log,
    const float* __restrict__ Dp, const float* __restrict__ hstart,
    ushort_t* ub)
{
    const int tid = threadIdx.x;
    const int b = blockIdx.x >> 7;
    const int p = (blockIdx.x >> 2) & 31;
    const int d = ((blockIdx.x & 3) << 8) + tid;
    const int t0 = p * CLEN;

    float A[D_STATE];
    #pragma unroll
    for (int n = 0; n < D_STATE; n++) A[n] = -expf(A_log[d * D_STATE + n]);
    const float Dv = Dp[d];

    float h[D_STATE];
    size_t base = (size_t)(b * PCH + p) * D_STATE * D_INNER + d;
    #pragma unroll
    for (int n = 0; n < D_STATE; n++) h[n] = hstart[base + (size_t)n * D_INNER];

    const float* dtp = dtb + ((size_t)b * SEQ + t0) * 1024 + d;
    const float* bp  = bc + ((size_t)b * SEQ + t0) * 64 + 32;
    const ushort_t* zp = xz + ((size_t)b * SEQ + t0) * 2048 + 1024 + d;
    ushort_t* up = ub + ((size_t)b * SEQ + t0) * D_INNER + d;

    for (int t = 0; t < CLEN; t++) {
        float dtv = dtp[(size_t)t * 1024];
        float uv  = bf2f(up[(size_t)t * D_INNER]);
        float zv  = bf2f(zp[(size_t)t * 2048]);
        float dtu = dtv * uv;
        float y = 0.f;
        #pragma unroll
        for (int n = 0; n < D_STATE; n++) {
            h[n] = fmaf(__expf(dtv * A[n]), h[n], dtu * bp[t * 64 + n]);
            y = fmaf(h[n], bp[t * 64 + 16 + n], y);
        }
        float res = fmaf(uv, Dv, y);
        res *= zv / (1.f + __expf(-zv));
        up[(size_t)t * D_INNER] = f2bf(res);
    }
}

// ---------------------------------------------------------------------------
__global__ __launch_bounds__(256) void softmax_kernel(
    const float* __restrict__ in, float* __restrict__ out)
{
    const int idx = blockIdx.x * 256 + threadIdx.x;
    float v = in[idx];
    float m = v;
    #pragma unroll
    for (int off = 16; off > 0; off >>= 1) m = fmaxf(m, __shfl_xor(m, off, 32));
    float e = expf(v - m);
    float s = e;
    #pragma unroll
    for (int off = 16; off > 0; off >>= 1) s += __shfl_xor(s, off, 32);
    out[idx] = e / s;
}

// ---------------------------------------------------------------------------
extern "C" void kernel_launch(void* const* d_in, const int* in_sizes, int n_in,
                              void* d_out, int out_size, void* d_ws, size_t ws_size,
                              hipStream_t stream)
{
    const float* x       = (const float*)d_in[0];
    const float* lin1_w  = (const float*)d_in[1];
    const float* lin1_b  = (const float*)d_in[2];
    const float* norm_w  = (const float*)d_in[3];
    const float* in_w    = (const float*)d_in[4];
    const float* conv_w  = (const float*)d_in[5];
    const float* conv_b  = (const float*)d_in[6];
    const float* xproj_w = (const float*)d_in[7];
    const float* dt_w    = (const float*)d_in[8];
    const float* dt_b    = (const float*)d_in[9];
    const float* A_log   = (const float*)d_in[10];
    const float* Dp      = (const float*)d_in[11];
    const float* out_w   = (const float*)d_in[12];
    const float* lin2_w  = (const float*)d_in[13];
    const float* lin2_b  = (const float*)d_in[14];
    float* outp = (float*)d_out;
    (void)ws_size; (void)in_sizes; (void)n_in; (void)out_size;

    float* ws = (float*)d_ws;
    const size_t F1M = 1u << 20;
    float* h     = ws;                             // 2M fl
    float* dtb   = h + 2 * F1M;                    // 4M fl (dt; also lin2 logits)
    float* dblr  = dtb + 4 * F1M;                  // 256K fl (low-rank xproj out)
    float* sumdt = dblr + (size_t)NTOK * 64;       // 128K fl
    float* hfin  = sumdt + (size_t)BATCH * PCH * D_INNER;  // 2M fl
    ushort_t* xzb     = (ushort_t*)(hfin + 2 * F1M);       // 8M us (xp|z, 2048)
    ushort_t* hn_bf   = xzb + 8 * F1M;                     // 2M us
    ushort_t* xb      = hn_bf + 2 * F1M;                   // 4M us
    ushort_t* dblr_bf = xb + 4 * F1M;                      // 256K us
    ushort_t* lin1_wt = dblr_bf + (size_t)NTOK * 64;       // 512*1024
    ushort_t* in_wt   = lin1_wt + (size_t)512 * 1024;      // 4*2048*512
    ushort_t* out_wt  = in_wt + (size_t)4 * 2048 * 512;    // 4*512*1024
    ushort_t* lin2_wt = out_wt + (size_t)4 * 512 * 1024;   // 1024*512
    ushort_t* xw_t    = lin2_wt + (size_t)1024 * 512;      // 4*64*1024
    ushort_t* w2t     = xw_t + (size_t)4 * 64 * 1024;      // 4*1024*64

    dim3 blk(256);

    // --- weight prep ---
    transpose_cast_kernel<<<dim3(512 / 32, 1024 / 32), blk, 0, stream>>>(
        lin1_w, lin1_wt, LATENT, D_MODEL);
    for (int l = 0; l < N_LAYERS; l++) {
        transpose_cast_kernel<<<dim3(2048 / 32, 512 / 32), blk, 0, stream>>>(
            in_w + (size_t)l * 512 * 2048, in_wt + (size_t)l * 2048 * 512, 512, 2048);
        transpose_cast_kernel<<<dim3(512 / 32, 1024 / 32), blk, 0, stream>>>(
            out_w + (size_t)l * 1024 * 512, out_wt + (size_t)l * 512 * 1024, 1024, 512);
        // xproj_w[l] is [k=1024][n=64] -> xw_t[l] is [n=64][k=1024] bf16
        transpose_cast_kernel<<<dim3(64 / 32, 1024 / 32), blk, 0, stream>>>(
            xproj_w + (size_t)l * D_INNER * 64, xw_t + (size_t)l * 64 * 1024, 1024, 64);
    }
    transpose_cast_kernel<<<dim3(1024 / 32, 512 / 32), blk, 0, stream>>>(
        lin2_w, lin2_wt, D_MODEL, LATENT);
    build_w2t_kernel<<<dim3((N_LAYERS * 1024 * 64) / 256), blk, 0, stream>>>(
        dt_w, w2t);

    // x -> bf16
    cast_bf16_kernel<<<dim3((NTOK * LATENT) / 256), blk, 0, stream>>>(x, xb);

    // lin1: h = x_bf @ lin1_wt^T + b  (fp32 out; 8x64=512 blocks)
    gemm_bf16_tile<<<dim3(D_MODEL / 64, NTOK / 64), blk, 0, stream>>>(
        xb, LATENT, lin1_wt, LATENT, h, nullptr, D_MODEL, lin1_b,
        NTOK, D_MODEL, LATENT, 1);

    for (int l = 0; l < N_LAYERS; l++) {
        const float* nw = norm_w + (size_t)l * D_MODEL;
        const float* cw = conv_w + (size_t)l * D_INNER * KCONV;
        const float* cb = conv_b + (size_t)l * D_INNER;
        const float* db = dt_b + (size_t)l * D_INNER;
        const float* al = A_log + (size_t)l * D_INNER * D_STATE;
        const float* dp = Dp + (size_t)l * D_INNER;
        const ushort_t* iwt = in_wt + (size_t)l * 2048 * 512;
        const ushort_t* owt = out_wt + (size_t)l * 512 * 1024;
        const ushort_t* xwt = xw_t + (size_t)l * 64 * 1024;
        const ushort_t* w2  = w2t + (size_t)l * 1024 * 64;

        rmsnorm_kernel<<<dim3(NTOK), blk, 0, stream>>>(h, nw, hn_bf);

        // fused in-proj: xzb = hn @ in_w[l]  (bf16 out; 32x64=2048 blocks)
        gemm_bf16_tile<<<dim3(2048 / 64, NTOK / 64), blk, 0, stream>>>(
            hn_bf, D_MODEL, iwt, D_MODEL, nullptr, xzb, 2048, nullptr,
            NTOK, 2048, D_MODEL, 8);

        // conv + silu: xzb[:, :1024] -> xb (bf16 u)
        conv_silu_kernel<<<dim3((NTOK * D_INNER) / 256), blk, 0, stream>>>(
            xzb, cw, cb, xb);

        // xproj LOW-RANK step A: dblr = u @ xproj_w[l]  (N=64, K=1024).
        // fp32 -> dblr (B/C for the scan) AND bf16 -> dblr_bf (flag 16).
        // 0.54 GF vs the old dense 9.66 GF. Grid 1x64 = 64 blocks.
        gemm_bf16_tile<<<dim3(64 / 64, NTOK / 64), blk, 0, stream>>>(
            xb, D_INNER, xwt, D_INNER, dblr, dblr_bf, 64, nullptr,
            NTOK, 64, D_INNER, 16);

        // step B: dtb = softplus(dblr_bf @ W2t^T + dt_b)  (N=1024, K=64,
        // one K-tile; W2t rows 32..63 are zero so B/C cols contribute 0).
        // Grid 16x64 = 1024 blocks; write-bound (~17 MB out).
        gemm_bf16_tile<<<dim3(1024 / 64, NTOK / 64), blk, 0, stream>>>(
            dblr_bf, 64, w2, 64, dtb, nullptr, 1024, db,
            NTOK, 1024, 64, 4);

        // chunked scan; pass3 overwrites xb in place with y*silu(z)
        scan_pass1<<<dim3(BATCH * PCH * (D_INNER / 256)), blk, 0, stream>>>(
            dtb, dblr, xb, al, hfin, sumdt);
        scan_pass2<<<dim3(BATCH * D_STATE * (D_INNER / 256)), blk, 0, stream>>>(
            al, sumdt, hfin);
        scan_pass3<<<dim3(BATCH * PCH * (D_INNER / 256)), blk, 0, stream>>>(
            dtb, dblr, xzb, al, dp, hfin, xb);

        // h += y_bf @ out_wt^T  (fp32 accumulate; 8x64=512 blocks)
        gemm_bf16_tile<<<dim3(D_MODEL / 64, NTOK / 64), blk, 0, stream>>>(
            xb, D_INNER, owt, D_INNER, h, nullptr, D_MODEL, nullptr,
            NTOK, D_MODEL, D_INNER, 2);
    }

    // h -> bf16, lin2 (logits into dtb), softmax
    cast_bf16_kernel<<<dim3((NTOK * D_MODEL) / 256), blk, 0, stream>>>(h, xb);
    gemm_bf16_tile<<<dim3(LATENT / 64, NTOK / 64), blk, 0, stream>>>(
        xb, D_MODEL, lin2_wt, D_MODEL, dtb, nullptr, LATENT, lin2_b,
        NTOK, LATENT, D_MODEL, 1);
    softmax_kernel<<<dim3((NTOK * LATENT) / 256), blk, 0, stream>>>(dtb, outp);
}

// Round 9
// 720.936 us; speedup vs baseline: 1.4938x; 1.0497x over previous
//
#include <hip/hip_runtime.h>
#include <math.h>

#define D_MODEL 512
#define N_LAYERS 4
#define LATENT 1024
#define D_INNER 1024
#define D_STATE 16
#define DT_RANK 32
#define KCONV 4
#define BATCH 4
#define SEQ 1024
#define NTOK (BATCH * SEQ) /* 4096 */
#define PCH 32
#define CLEN 32

typedef __attribute__((ext_vector_type(8))) short short8;
typedef __attribute__((ext_vector_type(4))) float floatx4;
typedef unsigned short ushort_t;

// gfx9 s_waitcnt immediates: vmcnt lo[3:0] hi[15:14], expcnt[6:4], lgkm[11:8]
#define WC_VM4   0x0F74  /* vmcnt(4) */
#define WC_VM0   0x0F70  /* vmcnt(0) */
#define WC_LGKM0 0xC07F  /* lgkmcnt(0), vm/exp free */

__device__ __forceinline__ ushort_t f2bf(float f) {
    union { float f; unsigned u; } v; v.f = f;
    unsigned r = v.u + 0x7FFFu + ((v.u >> 16) & 1u);  // RNE
    return (ushort_t)(r >> 16);
}
__device__ __forceinline__ float bf2f(ushort_t u) {
    union { unsigned u; float f; } v; v.u = ((unsigned)u) << 16;
    return v.f;
}
// async global -> LDS, 16B per lane (verified width=16 on gfx950, m97).
__device__ __forceinline__ void gll16(const void* g, void* l) {
    __builtin_amdgcn_global_load_lds(
        (const __attribute__((address_space(1))) void*)g,
        (__attribute__((address_space(3))) void*)l, 16, 0, 0);
}

// ---------------------------------------------------------------------------
// bf16 MFMA GEMM, 64x64 tile (r3 structure — proven across 4 passing runs):
// triple-buffered LDS, distance-2 prefetch, single barrier per iter, XOR-8
// swizzle (conflicts=0), XCD-chunked bijective remap (FETCH 37.6->18MB).
// flags: 1 = add bias[n], 2 = accumulate into C (fp32),
//        4 = softplus(v + bias[n]) for n<1024,
//        8 = write bf16 to Cb only.
// ---------------------------------------------------------------------------
__global__ __launch_bounds__(256, 3) void gemm_bf16_tile(
    const ushort_t* __restrict__ A, int lda,
    const ushort_t* __restrict__ Bt, int ldb,
    float* __restrict__ C, ushort_t* __restrict__ Cb, int ldc,
    const float* __restrict__ bias,
    int M, int N, int K, int flags)
{
    __shared__ ushort_t As[3][4096];   // 3 x 8 KB
    __shared__ ushort_t Bs[3][4096];   // 3 x 8 KB

    const int gx = gridDim.x;
    const int nwg = gx * gridDim.y;
    const int orig = blockIdx.y * gx + blockIdx.x;
    const int qq = nwg >> 3, rr = nwg & 7;
    const int xcd = orig & 7, loc = orig >> 3;
    const int swz = (xcd < rr ? xcd * (qq + 1) : rr * (qq + 1) + (xcd - rr) * qq) + loc;
    const int m0 = (swz / gx) * 64;
    const int n0 = (swz % gx) * 64;

    const int tid = threadIdx.x;
    const int w = tid >> 6;
    const int lane = tid & 63;
    const int quad = lane >> 4;
    const int l16 = lane & 15;
    const int wm = (w & 1) * 32;
    const int wn = (w >> 1) * 32;

    const int srow = tid >> 3;
    const int schunk = ((tid & 7) ^ (srow & 7)) * 8;
    const ushort_t* ga = A + (size_t)(m0 + srow) * lda + schunk;
    const ushort_t* gb = Bt + (size_t)(n0 + srow) * ldb + schunk;
    const int lofs = tid * 8;

    const int swz0 = ((0 * 4 + quad) ^ (l16 & 7)) * 8;
    const int swz1 = ((1 * 4 + quad) ^ (l16 & 7)) * 8;

    floatx4 acc[2][2] = {};
    const int nt = K >> 6;

    #define STAGE(t, b)                                         \
        do {                                                    \
            const ushort_t* pa_ = ga + (t) * 64;                \
            const ushort_t* pb_ = gb + (t) * 64;                \
            gll16(pa_, &As[(b)][lofs]);                         \
            gll16(pa_ + (size_t)32 * lda, &As[(b)][2048 + lofs]); \
            gll16(pb_, &Bs[(b)][lofs]);                         \
            gll16(pb_ + (size_t)32 * ldb, &Bs[(b)][2048 + lofs]); \
        } while (0)

    STAGE(0, 0);
    if (nt > 1) STAGE(1, 1);

    int cur = 0;
    for (int kt = 0; kt < nt; kt++) {
        if (kt + 1 < nt) __builtin_amdgcn_s_waitcnt(WC_VM4);
        else             __builtin_amdgcn_s_waitcnt(WC_VM0);
        __builtin_amdgcn_s_barrier();
        __builtin_amdgcn_sched_barrier(0);

        if (kt + 2 < nt) {
            int nb = cur + 2; if (nb >= 3) nb -= 3;
            STAGE(kt + 2, nb);
        }

        short8 af[2][2], bfr[2][2];
        #pragma unroll
        for (int i = 0; i < 2; i++) {
            const int r = wm + i * 16 + l16;
            af[0][i] = *(const short8*)&As[cur][r * 64 + swz0];
            af[1][i] = *(const short8*)&As[cur][r * 64 + swz1];
        }
        #pragma unroll
        for (int j = 0; j < 2; j++) {
            const int r = wn + j * 16 + l16;
            bfr[0][j] = *(const short8*)&Bs[cur][r * 64 + swz0];
            bfr[1][j] = *(const short8*)&Bs[cur][r * 64 + swz1];
        }
        __builtin_amdgcn_s_waitcnt(WC_LGKM0);
        __builtin_amdgcn_sched_barrier(0);

        #pragma unroll
        for (int ks = 0; ks < 2; ks++)
            #pragma unroll
            for (int i = 0; i < 2; i++)
                #pragma unroll
                for (int j = 0; j < 2; j++)
                    acc[i][j] = __builtin_amdgcn_mfma_f32_16x16x32_bf16(
                        af[ks][i], bfr[ks][j], acc[i][j], 0, 0, 0);

        cur++; if (cur == 3) cur = 0;
    }
    #undef STAGE

    // C/D layout (m89-verified): col = lane&15, row = quad*4 + reg.
    #pragma unroll
    for (int j = 0; j < 2; j++) {
        int n = n0 + wn + j * 16 + l16;
        float bv = (flags & 1) ? bias[n] : 0.f;
        bool do_sp = (flags & 4) && (n < 1024);
        float spb = do_sp ? bias[n] : 0.f;
        #pragma unroll
        for (int i = 0; i < 2; i++) {
            int mrow = m0 + wm + i * 16 + quad * 4;
            #pragma unroll
            for (int rr2 = 0; rr2 < 4; rr2++) {
                size_t idx = (size_t)(mrow + rr2) * ldc + n;
                float v = acc[i][j][rr2] + bv;
                if (do_sp) {
                    v += spb;
                    v = (v > 20.f) ? v : log1pf(__expf(v));
                }
                if (flags & 8) {
                    Cb[idx] = f2bf(v);
                } else {
                    if (flags & 2) v += C[idx];
                    C[idx] = v;
                }
            }
        }
    }
}

// ---------------------------------------------------------------------------
// stepA split-K GEMM: Cpart[kq] = u[:, kq*256:(kq+1)*256] @ xw_t^T (N=64).
// r8 evidence: stepA at grid (1,64) = 64 blocks left 75% of CUs idle and
// ran a serial 16-K-step chain (~10-12us inferred). Split K by 4:
// grid (4,64) = 256 blocks (1/CU), chain 4 steps. Partials reduced by
// reduce_dblr. Same staging/swizzle/loop body as gemm_bf16_tile.
// ---------------------------------------------------------------------------
__global__ __launch_bounds__(256, 3) void gemm_stepA(
    const ushort_t* __restrict__ A,   // [NTOK][1024] bf16 (u)
    const ushort_t* __restrict__ Bt,  // [64][1024] bf16 (xw_t)
    float* __restrict__ Cpart)        // [4][NTOK][64]
{
    __shared__ ushort_t As[3][4096];
    __shared__ ushort_t Bs[3][4096];

    const int kq = blockIdx.x;          // 0..3 (K window)
    const int m0 = blockIdx.y * 64;
    const int k0 = kq * 256;

    const int tid = threadIdx.x;
    const int w = tid >> 6;
    const int lane = tid & 63;
    const int quad = lane >> 4;
    const int l16 = lane & 15;
    const int wm = (w & 1) * 32;
    const int wn = (w >> 1) * 32;

    const int srow = tid >> 3;
    const int schunk = ((tid & 7) ^ (srow & 7)) * 8;
    const ushort_t* ga = A + (size_t)(m0 + srow) * 1024 + k0 + schunk;
    const ushort_t* gb = Bt + (size_t)srow * 1024 + k0 + schunk;
    const int lofs = tid * 8;

    const int swz0 = ((0 * 4 + quad) ^ (l16 & 7)) * 8;
    const int swz1 = ((1 * 4 + quad) ^ (l16 & 7)) * 8;

    floatx4 acc[2][2] = {};
    const int nt = 4;

    #define STAGE(t, b)                                            \
        do {                                                       \
            const ushort_t* pa_ = ga + (t) * 64;                   \
            const ushort_t* pb_ = gb + (t) * 64;                   \
            gll16(pa_, &As[(b)][lofs]);                            \
            gll16(pa_ + (size_t)32 * 1024, &As[(b)][2048 + lofs]); \
            gll16(pb_, &Bs[(b)][lofs]);                            \
            gll16(pb_ + (size_t)32 * 1024, &Bs[(b)][2048 + lofs]); \
        } while (0)

    STAGE(0, 0);
    STAGE(1, 1);

    int cur = 0;
    for (int kt = 0; kt < nt; kt++) {
        if (kt + 1 < nt) __builtin_amdgcn_s_waitcnt(WC_VM4);
        else             __builtin_amdgcn_s_waitcnt(WC_VM0);
        __builtin_amdgcn_s_barrier();
        __builtin_amdgcn_sched_barrier(0);

        if (kt + 2 < nt) {
            int nb = cur + 2; if (nb >= 3) nb -= 3;
            STAGE(kt + 2, nb);
        }

        short8 af[2][2], bfr[2][2];
        #pragma unroll
        for (int i = 0; i < 2; i++) {
            const int r = wm + i * 16 + l16;
            af[0][i] = *(const short8*)&As[cur][r * 64 + swz0];
            af[1][i] = *(const short8*)&As[cur][r * 64 + swz1];
        }
        #pragma unroll
        for (int j = 0; j < 2; j++) {
            const int r = wn + j * 16 + l16;
            bfr[0][j] = *(const short8*)&Bs[cur][r * 64 + swz0];
            bfr[1][j] = *(const short8*)&Bs[cur][r * 64 + swz1];
        }
        __builtin_amdgcn_s_waitcnt(WC_LGKM0);
        __builtin_amdgcn_sched_barrier(0);

        #pragma unroll
        for (int ks = 0; ks < 2; ks++)
            #pragma unroll
            for (int i = 0; i < 2; i++)
                #pragma unroll
                for (int j = 0; j < 2; j++)
                    acc[i][j] = __builtin_amdgcn_mfma_f32_16x16x32_bf16(
                        af[ks][i], bfr[ks][j], acc[i][j], 0, 0, 0);

        cur++; if (cur == 3) cur = 0;
    }
    #undef STAGE

    float* Cp = Cpart + (size_t)kq * NTOK * 64;
    #pragma unroll
    for (int j = 0; j < 2; j++) {
        int n = wn + j * 16 + l16;
        #pragma unroll
        for (int i = 0; i < 2; i++) {
            int mrow = m0 + wm + i * 16 + quad * 4;
            #pragma unroll
            for (int rr2 = 0; rr2 < 4; rr2++)
                Cp[(size_t)(mrow + rr2) * 64 + n] = acc[i][j][rr2];
        }
    }
}

// ---------------------------------------------------------------------------
// reduce_dblr: dblr = sum of 4 split-K partials (fp32) + bf16 copy for stepB.
// ---------------------------------------------------------------------------
__global__ __launch_bounds__(256) void reduce_dblr(
    const float* __restrict__ part, float* __restrict__ dblr,
    ushort_t* __restrict__ dblr_bf)
{
    const int i = blockIdx.x * 256 + threadIdx.x;
    const size_t st = (size_t)NTOK * 64;
    float s = part[i] + part[i + st] + part[i + 2 * st] + part[i + 3 * st];
    dblr[i] = s;
    dblr_bf[i] = f2bf(s);
}

// ---------------------------------------------------------------------------
// build_w2t: W2t[l][n][k] = (k<32) ? bf16(dt_w[l][k][n]) : 0.
// (Pad MUST be written every launch: d_ws is re-poisoned to 0xAA.)
// ---------------------------------------------------------------------------
__global__ __launch_bounds__(256) void build_w2t_kernel(
    const float* __restrict__ dt_w, ushort_t* __restrict__ w2t)
{
    const int idx = blockIdx.x * 256 + threadIdx.x;
    const int k = idx & 63;
    const int n = (idx >> 6) & 1023;
    const int l = idx >> 16;
    ushort_t v = 0;
    if (k < 32)
        v = f2bf(dt_w[((size_t)l * DT_RANK + k) * D_INNER + n]);
    w2t[((size_t)l * 1024 + n) * 64 + k] = v;
}

// ---------------------------------------------------------------------------
// Batched transpose+cast: z-dim = layer (r9: 14 prep launches -> 6).
// in[l][K][N] -> out[l][N][K] bf16.
// ---------------------------------------------------------------------------
__global__ __launch_bounds__(256) void transpose_cast_b(
    const float* __restrict__ in0, ushort_t* __restrict__ out0, int K, int N,
    size_t in_ls, size_t out_ls)
{
    const float* in = in0 + (size_t)blockIdx.z * in_ls;
    ushort_t* out = out0 + (size_t)blockIdx.z * out_ls;
    __shared__ float tile[32][33];
    const int n0 = blockIdx.x * 32, k0 = blockIdx.y * 32;
    const int tx = threadIdx.x & 31, ty = threadIdx.x >> 5;
    #pragma unroll
    for (int i = 0; i < 4; i++)
        tile[ty + i * 8][tx] = in[(size_t)(k0 + ty + i * 8) * N + n0 + tx];
    __syncthreads();
    #pragma unroll
    for (int i = 0; i < 4; i++)
        out[(size_t)(n0 + ty + i * 8) * K + k0 + tx] = f2bf(tile[tx][ty + i * 8]);
}

// ---------------------------------------------------------------------------
__global__ __launch_bounds__(256) void cast_bf16_kernel(
    const float* __restrict__ in, ushort_t* __restrict__ out)
{
    const int i = blockIdx.x * 256 + threadIdx.x;
    out[i] = f2bf(in[i]);
}

// ---------------------------------------------------------------------------
__global__ __launch_bounds__(256) void rmsnorm_kernel(
    const float* __restrict__ x, const float* __restrict__ w,
    ushort_t* __restrict__ y)
{
    const int row = blockIdx.x;
    const float* xr = x + (size_t)row * D_MODEL;
    ushort_t* yr = y + (size_t)row * D_MODEL;
    const int tid = threadIdx.x;

    float v0 = xr[tid], v1 = xr[tid + 256];
    float ss = v0 * v0 + v1 * v1;
    #pragma unroll
    for (int off = 32; off > 0; off >>= 1) ss += __shfl_down(ss, off);

    __shared__ float wsum[4];
    __shared__ float scale_s;
    int wid = tid >> 6, lane = tid & 63;
    if (lane == 0) wsum[wid] = ss;
    __syncthreads();
    if (tid == 0) {
        float tot = wsum[0] + wsum[1] + wsum[2] + wsum[3];
        scale_s = 1.0f / sqrtf(tot / (float)D_MODEL + 1e-5f);
    }
    __syncthreads();
    float sc = scale_s;
    yr[tid] = f2bf(v0 * sc * w[tid]);
    yr[tid + 256] = f2bf(v1 * sc * w[tid + 256]);
}

// ---------------------------------------------------------------------------
// Causal dwconv (K=4) + bias + silu. Reads bf16 xz (stride 2048, xp plane),
// writes bf16 u.
// ---------------------------------------------------------------------------
__global__ __launch_bounds__(256) void conv_silu_kernel(
    const ushort_t* __restrict__ xz, const float* __restrict__ w,
    const float* __restrict__ bconv, ushort_t* __restrict__ outb)
{
    const int idx = blockIdx.x * 256 + threadIdx.x;
    const int d = idx & (D_INNER - 1);
    const int t = (idx >> 10) & (SEQ - 1);
    const int row = idx >> 10;
    const ushort_t* base = xz + (size_t)row * 2048 + d;

    float s = 0.f;
    #pragma unroll
    for (int k = 0; k < KCONV; k++) {
        int tt = t + k - (KCONV - 1);
        if (tt >= 0)
            s = fmaf(bf2f(base[(ptrdiff_t)(k - (KCONV - 1)) * 2048]), w[d * KCONV + k], s);
    }
    s += bconv[d];
    float r = s / (1.f + __expf(-s));
    outb[idx] = f2bf(r);
}

// ---------------------------------------------------------------------------
// Chunked selective scan (3 passes), CLEN=32.
// dt in dtb (stride 1024, already softplus'ed); B/C in bc (stride 64):
// bc[row][32+n]=B[n], bc[row][48+n]=C[n]. u bf16 in ub; z bf16 in xz[:,1024:].
// ---------------------------------------------------------------------------
__global__ __launch_bounds__(256) void scan_pass1(
    const float* __restrict__ dtb, const float* __restrict__ bc,
    const ushort_t* __restrict__ ub, const float* __restrict__ A_log,
    float* __restrict__ hfin, float* __restrict__ sumdt)
{
    const int tid = threadIdx.x;
    const int b = blockIdx.x >> 7;
    const int p = (blockIdx.x >> 2) & 31;
    const int d = ((blockIdx.x & 3) << 8) + tid;
    const int t0 = p * CLEN;

    float A[D_STATE];
    #pragma unroll
    for (int n = 0; n < D_STATE; n++) A[n] = -expf(A_log[d * D_STATE + n]);

    float h[D_STATE] = {};
    float sdt = 0.f;

    const float* dtp = dtb + ((size_t)b * SEQ + t0) * 1024 + d;
    const float* bp  = bc + ((size_t)b * SEQ + t0) * 64 + 32;
    const ushort_t* up = ub + ((size_t)b * SEQ + t0) * D_INNER + d;

    for (int t = 0; t < CLEN; t++) {
        float dtv = dtp[(size_t)t * 1024];
        float uv  = bf2f(up[(size_t)t * D_INNER]);
        float dtu = dtv * uv;
        sdt += dtv;
        #pragma unroll
        for (int n = 0; n < D_STATE; n++)
            h[n] = fmaf(__expf(dtv * A[n]), h[n], dtu * bp[t * 64 + n]);
    }

    size_t base = (size_t)(b * PCH + p) * D_STATE * D_INNER + d;
    #pragma unroll
    for (int n = 0; n < D_STATE; n++) hfin[base + (size_t)n * D_INNER] = h[n];
    sumdt[(size_t)(b * PCH + p) * D_INNER + d] = sdt;
}

// r9: preload all 32 chunk-final states + sumdt (independent loads, ~64
// VGPR, static unroll per rule #20), THEN run the serial recurrence as
// pure VALU with fire-and-forget writes. Replaces 32 dependent global
// read->write round-trips (~600 cyc each) with one parallel load burst.
__global__ __launch_bounds__(256) void scan_pass2(
    const float* __restrict__ A_log, const float* __restrict__ sumdt,
    float* __restrict__ hc)
{
    const int tid = threadIdx.x;
    const int b = blockIdx.x >> 6;
    const int n = (blockIdx.x >> 2) & 15;
    const int d = ((blockIdx.x & 3) << 8) + tid;

    const float Aval = -expf(A_log[d * D_STATE + n]);

    float fin[PCH], sd[PCH];
    #pragma unroll
    for (int p = 0; p < PCH; p++) {
        fin[p] = hc[((size_t)(b * PCH + p) * D_STATE + n) * D_INNER + d];
        sd[p]  = sumdt[(size_t)(b * PCH + p) * D_INNER + d];
    }
    float h = 0.f;
    #pragma unroll
    for (int p = 0; p < PCH; p++) {
        hc[((size_t)(b * PCH + p) * D_STATE + n) * D_INNER + d] = h;
        h = fmaf(__expf(Aval * sd[p]), h, fin[p]);
    }
}

// pass3: u (bf16, in ub) read then overwritten IN PLACE with y*silu(z).
__global__ __launch_bounds__(256) void scan_pass3(
    const float* __restrict__ dtb, const float* __restrict__ bc,
    const ushort_t* __restrict__ xz, const float* __restrict__ A_log,
    const float* __restrict__ Dp, const float* __restrict__ hstart,
    ushort_t* ub)
{
    const int tid = threadIdx.x;
    const int b = blockIdx.x >> 7;
    const int p = (blockIdx.x >> 2) & 31;
    const int d = ((blockIdx.x & 3) << 8) + tid;
    const int t0 = p * CLEN;

    float A[D_STATE];
    #pragma unroll
    for (int n = 0; n < D_STATE; n++) A[n] = -expf(A_log[d * D_STATE + n]);
    const float Dv = Dp[d];

    float h[D_STATE];
    size_t base = (size_t)(b * PCH + p) * D_STATE * D_INNER + d;
    #pragma unroll
    for (int n = 0; n < D_STATE; n++) h[n] = hstart[base + (size_t)n * D_INNER];

    const float* dtp = dtb + ((size_t)b * SEQ + t0) * 1024 + d;
    const float* bp  = bc + ((size_t)b * SEQ + t0) * 64 + 32;
    const ushort_t* zp = xz + ((size_t)b * SEQ + t0) * 2048 + 1024 + d;
    ushort_t* up = ub + ((size_t)b * SEQ + t0) * D_INNER + d;

    for (int t = 0; t < CLEN; t++) {
        float dtv = dtp[(size_t)t * 1024];
        float uv  = bf2f(up[(size_t)t * D_INNER]);
        float zv  = bf2f(zp[(size_t)t * 2048]);
        float dtu = dtv * uv;
        float y = 0.f;
        #pragma unroll
        for (int n = 0; n < D_STATE; n++) {
            h[n] = fmaf(__expf(dtv * A[n]), h[n], dtu * bp[t * 64 + n]);
            y = fmaf(h[n], bp[t * 64 + 16 + n], y);
        }
        float res = fmaf(uv, Dv, y);
        res *= zv / (1.f + __expf(-zv));
        up[(size_t)t * D_INNER] = f2bf(res);
    }
}

// ---------------------------------------------------------------------------
__global__ __launch_bounds__(256) void softmax_kernel(
    const float* __restrict__ in, float* __restrict__ out)
{
    const int idx = blockIdx.x * 256 + threadIdx.x;
    float v = in[idx];
    float m = v;
    #pragma unroll
    for (int off = 16; off > 0; off >>= 1) m = fmaxf(m, __shfl_xor(m, off, 32));
    float e = expf(v - m);
    float s = e;
    #pragma unroll
    for (int off = 16; off > 0; off >>= 1) s += __shfl_xor(s, off, 32);
    out[idx] = e / s;
}

// ---------------------------------------------------------------------------
extern "C" void kernel_launch(void* const* d_in, const int* in_sizes, int n_in,
                              void* d_out, int out_size, void* d_ws, size_t ws_size,
                              hipStream_t stream)
{
    const float* x       = (const float*)d_in[0];
    const float* lin1_w  = (const float*)d_in[1];
    const float* lin1_b  = (const float*)d_in[2];
    const float* norm_w  = (const float*)d_in[3];
    const float* in_w    = (const float*)d_in[4];
    const float* conv_w  = (const float*)d_in[5];
    const float* conv_b  = (const float*)d_in[6];
    const float* xproj_w = (const float*)d_in[7];
    const float* dt_w    = (const float*)d_in[8];
    const float* dt_b    = (const float*)d_in[9];
    const float* A_log   = (const float*)d_in[10];
    const float* Dp      = (const float*)d_in[11];
    const float* out_w   = (const float*)d_in[12];
    const float* lin2_w  = (const float*)d_in[13];
    const float* lin2_b  = (const float*)d_in[14];
    float* outp = (float*)d_out;
    (void)ws_size; (void)in_sizes; (void)n_in; (void)out_size;

    float* ws = (float*)d_ws;
    const size_t F1M = 1u << 20;
    float* h     = ws;                                  // 2M fl
    float* dtb   = h + 2 * F1M;                         // 4M fl (dt; lin2 logits)
    float* dblr  = dtb + 4 * F1M;                       // 256K fl
    float* dpart = dblr + (size_t)NTOK * 64;            // 1M fl (4 split-K partials)
    float* sumdt = dpart + (size_t)4 * NTOK * 64;       // 128K fl
    float* hfin  = sumdt + (size_t)BATCH * PCH * D_INNER;  // 2M fl
    ushort_t* xzb     = (ushort_t*)(hfin + 2 * F1M);       // 8M us (xp|z, 2048)
    ushort_t* hn_bf   = xzb + 8 * F1M;                     // 2M us
    ushort_t* xb      = hn_bf + 2 * F1M;                   // 4M us
    ushort_t* dblr_bf = xb + 4 * F1M;                      // 256K us
    ushort_t* lin1_wt = dblr_bf + (size_t)NTOK * 64;       // 512*1024
    ushort_t* in_wt   = lin1_wt + (size_t)512 * 1024;      // 4*2048*512
    ushort_t* out_wt  = in_wt + (size_t)4 * 2048 * 512;    // 4*512*1024
    ushort_t* lin2_wt = out_wt + (size_t)4 * 512 * 1024;   // 1024*512
    ushort_t* xw_t    = lin2_wt + (size_t)1024 * 512;      // 4*64*1024
    ushort_t* w2t     = xw_t + (size_t)4 * 64 * 1024;      // 4*1024*64

    dim3 blk(256);

    // --- weight prep (batched: 6 launches, was 14) ---
    transpose_cast_b<<<dim3(512 / 32, 1024 / 32, 1), blk, 0, stream>>>(
        lin1_w, lin1_wt, LATENT, D_MODEL, 0, 0);
    transpose_cast_b<<<dim3(2048 / 32, 512 / 32, N_LAYERS), blk, 0, stream>>>(
        in_w, in_wt, 512, 2048, (size_t)512 * 2048, (size_t)2048 * 512);
    transpose_cast_b<<<dim3(512 / 32, 1024 / 32, N_LAYERS), blk, 0, stream>>>(
        out_w, out_wt, 1024, 512, (size_t)1024 * 512, (size_t)512 * 1024);
    transpose_cast_b<<<dim3(64 / 32, 1024 / 32, N_LAYERS), blk, 0, stream>>>(
        xproj_w, xw_t, 1024, 64, (size_t)1024 * 64, (size_t)64 * 1024);
    transpose_cast_b<<<dim3(1024 / 32, 512 / 32, 1), blk, 0, stream>>>(
        lin2_w, lin2_wt, D_MODEL, LATENT, 0, 0);
    build_w2t_kernel<<<dim3((N_LAYERS * 1024 * 64) / 256), blk, 0, stream>>>(
        dt_w, w2t);

    // x -> bf16
    cast_bf16_kernel<<<dim3((NTOK * LATENT) / 256), blk, 0, stream>>>(x, xb);

    // lin1: h = x_bf @ lin1_wt^T + b  (fp32 out; 8x64=512 blocks)
    gemm_bf16_tile<<<dim3(D_MODEL / 64, NTOK / 64), blk, 0, stream>>>(
        xb, LATENT, lin1_wt, LATENT, h, nullptr, D_MODEL, lin1_b,
        NTOK, D_MODEL, LATENT, 1);

    for (int l = 0; l < N_LAYERS; l++) {
        const float* nw = norm_w + (size_t)l * D_MODEL;
        const float* cw = conv_w + (size_t)l * D_INNER * KCONV;
        const float* cb = conv_b + (size_t)l * D_INNER;
        const float* db = dt_b + (size_t)l * D_INNER;
        const float* al = A_log + (size_t)l * D_INNER * D_STATE;
        const float* dp = Dp + (size_t)l * D_INNER;
        const ushort_t* iwt = in_wt + (size_t)l * 2048 * 512;
        const ushort_t* owt = out_wt + (size_t)l * 512 * 1024;
        const ushort_t* xwt = xw_t + (size_t)l * 64 * 1024;
        const ushort_t* w2  = w2t + (size_t)l * 1024 * 64;

        rmsnorm_kernel<<<dim3(NTOK), blk, 0, stream>>>(h, nw, hn_bf);

        // fused in-proj: xzb = hn @ in_w[l]  (bf16 out; 32x64=2048 blocks)
        gemm_bf16_tile<<<dim3(2048 / 64, NTOK / 64), blk, 0, stream>>>(
            hn_bf, D_MODEL, iwt, D_MODEL, nullptr, xzb, 2048, nullptr,
            NTOK, 2048, D_MODEL, 8);

        // conv + silu: xzb[:, :1024] -> xb (bf16 u)
        conv_silu_kernel<<<dim3((NTOK * D_INNER) / 256), blk, 0, stream>>>(
            xzb, cw, cb, xb);

        // xproj step A (split-K x4): dpart[kq] = u @ xw_t^T  (4x64=256 blocks)
        gemm_stepA<<<dim3(4, NTOK / 64), blk, 0, stream>>>(xb, xwt, dpart);
        // reduce partials -> dblr fp32 (B/C for scan) + dblr_bf for stepB
        reduce_dblr<<<dim3((NTOK * 64) / 256), blk, 0, stream>>>(
            dpart, dblr, dblr_bf);

        // step B: dtb = softplus(dblr_bf @ W2t^T + dt_b)  (N=1024, K=64,
        // one K-tile; W2t rows 32..63 zero -> B/C cols contribute 0).
        gemm_bf16_tile<<<dim3(1024 / 64, NTOK / 64), blk, 0, stream>>>(
            dblr_bf, 64, w2, 64, dtb, nullptr, 1024, db,
            NTOK, 1024, 64, 4);

        // chunked scan; pass3 overwrites xb in place with y*silu(z)
        scan_pass1<<<dim3(BATCH * PCH * (D_INNER / 256)), blk, 0, stream>>>(
            dtb, dblr, xb, al, hfin, sumdt);
        scan_pass2<<<dim3(BATCH * D_STATE * (D_INNER / 256)), blk, 0, stream>>>(
            al, sumdt, hfin);
        scan_pass3<<<dim3(BATCH * PCH * (D_INNER / 256)), blk, 0, stream>>>(
            dtb, dblr, xzb, al, dp, hfin, xb);

        // h += y_bf @ out_wt^T  (fp32 accumulate; 8x64=512 blocks)
        gemm_bf16_tile<<<dim3(D_MODEL / 64, NTOK / 64), blk, 0, stream>>>(
            xb, D_INNER, owt, D_INNER, h, nullptr, D_MODEL, nullptr,
            NTOK, D_MODEL, D_INNER, 2);
    }

    // h -> bf16, lin2 (logits into dtb), softmax
    cast_bf16_kernel<<<dim3((NTOK * D_MODEL) / 256), blk, 0, stream>>>(h, xb);
    gemm_bf16_tile<<<dim3(LATENT / 64, NTOK / 64), blk, 0, stream>>>(
        xb, D_MODEL, lin2_wt, D_MODEL, dtb, nullptr, LATENT, lin2_b,
        NTOK, LATENT, D_MODEL, 1);
    softmax_kernel<<<dim3((NTOK * LATENT) / 256), blk, 0, stream>>>(dtb, outp);
}

// Round 10
// 709.197 us; speedup vs baseline: 1.5185x; 1.0166x over previous
//
#include <hip/hip_runtime.h>
#include <math.h>

#define D_MODEL 512
#define N_LAYERS 4
#define LATENT 1024
#define D_INNER 1024
#define D_STATE 16
#define DT_RANK 32
#define KCONV 4
#define BATCH 4
#define SEQ 1024
#define NTOK (BATCH * SEQ) /* 4096 */
#define PCH 32
#define CLEN 32

typedef __attribute__((ext_vector_type(8))) short short8;
typedef __attribute__((ext_vector_type(4))) float floatx4;
typedef unsigned short ushort_t;

// gfx9 s_waitcnt immediates: vmcnt lo[3:0] hi[15:14], expcnt[6:4], lgkm[11:8]
#define WC_VM4   0x0F74  /* vmcnt(4) */
#define WC_VM8   0x0F78  /* vmcnt(8) */
#define WC_VM0   0x0F70  /* vmcnt(0) */
#define WC_LGKM0 0xC07F  /* lgkmcnt(0), vm/exp free */

__device__ __forceinline__ ushort_t f2bf(float f) {
    union { float f; unsigned u; } v; v.f = f;
    unsigned r = v.u + 0x7FFFu + ((v.u >> 16) & 1u);  // RNE
    return (ushort_t)(r >> 16);
}
__device__ __forceinline__ float bf2f(ushort_t u) {
    union { unsigned u; float f; } v; v.u = ((unsigned)u) << 16;
    return v.f;
}
// async global -> LDS, 16B per lane (verified width=16 on gfx950, m97).
__device__ __forceinline__ void gll16(const void* g, void* l) {
    __builtin_amdgcn_global_load_lds(
        (const __attribute__((address_space(1))) void*)g,
        (__attribute__((address_space(3))) void*)l, 16, 0, 0);
}

// ---------------------------------------------------------------------------
// 256x256 2-phase GEMM (inproj only): bf16 out = A[M,K] @ Bt[N,K]^T.
// r10 theory: guide's m230/m248 anchor shows a plain 2-phase 256^2 tile
// reaches 655-682 TF (3.4x our 64^2's ~195) — per-wave 128x64 output via
// 8x4 frags gives 64 MFMA per sync point (4x) and ~512 B LDS per MFMA.
// Schedule = the r0-PROVEN loop (double-buffer, stage-then-counted-vmcnt,
// 2 barriers/K-step, XOR-8 swizzle, XCD remap), just re-parameterized:
// 512 threads / 8 waves (2M x 4N), LDS 2x(32+32) KB = 128 KB, NO
// sched_barrier pins (r6: pins cost 20% on wide tiles).
// k-slices read+MFMA'd sequentially to keep VGPR ~200 (<256 @ 2 waves/SIMD).
// ---------------------------------------------------------------------------
__global__ __launch_bounds__(512, 2) void gemm_bf16_t256(
    const ushort_t* __restrict__ A, int lda,
    const ushort_t* __restrict__ Bt, int ldb,
    ushort_t* __restrict__ Cb, int ldc,
    int M, int N, int K)
{
    __shared__ ushort_t As[2][16384];   // [buf][256 rows x 64 cols]
    __shared__ ushort_t Bs[2][16384];

    // XCD-chunked bijective remap (nwg % 8 == 0).
    const int gx = gridDim.x;
    const int nwg = gx * gridDim.y;
    const int orig = blockIdx.y * gx + blockIdx.x;
    const int qq = nwg >> 3, rr = nwg & 7;
    const int xcd = orig & 7, loc = orig >> 3;
    const int swz = (xcd < rr ? xcd * (qq + 1) : rr * (qq + 1) + (xcd - rr) * qq) + loc;
    const int m0 = (swz / gx) * 256;
    const int n0 = (swz % gx) * 256;

    const int tid = threadIdx.x;          // 0..511
    const int w = tid >> 6;               // 0..7
    const int lane = tid & 63;
    const int quad = lane >> 4;
    const int l16 = lane & 15;
    const int wm = (w & 1) * 128;         // wave grid 2M x 4N
    const int wn = (w >> 1) * 64;

    // staging: 64 rows per sweep (8 threads/row), 4 sweeps per matrix.
    const int srow = tid >> 3;                     // 0..63
    const int schunk = ((tid & 7) ^ (srow & 7)) * 8;
    const ushort_t* ga = A + (size_t)(m0 + srow) * lda + schunk;
    const ushort_t* gb = Bt + (size_t)(n0 + srow) * ldb + schunk;
    const int lofs = tid * 8;                      // 4096 elems per sweep

    const int swz0 = ((0 * 4 + quad) ^ (l16 & 7)) * 8;
    const int swz1 = ((1 * 4 + quad) ^ (l16 & 7)) * 8;

    floatx4 acc[8][4] = {};
    const int nt = K >> 6;

    // 8 VMEM ops per thread per K-tile (4 A-sweeps + 4 B-sweeps).
    #define STAGE(t, b)                                                         \
        do {                                                                    \
            const ushort_t* pa_ = ga + (t) * 64;                                \
            const ushort_t* pb_ = gb + (t) * 64;                                \
            _Pragma("unroll")                                                   \
            for (int q = 0; q < 4; q++) {                                       \
                gll16(pa_ + (size_t)(q * 64) * lda, &As[(b)][q * 4096 + lofs]); \
                gll16(pb_ + (size_t)(q * 64) * ldb, &Bs[(b)][q * 4096 + lofs]); \
            }                                                                   \
        } while (0)

    STAGE(0, 0);

    for (int kt = 0; kt < nt; kt++) {
        const int cur = kt & 1;
        if (kt + 1 < nt) {
            STAGE(kt + 1, 1 - cur);              // 8 newer ops in flight
            __builtin_amdgcn_s_waitcnt(WC_VM8);  // tile kt fully landed
        } else {
            __builtin_amdgcn_s_waitcnt(WC_VM0);
        }
        __builtin_amdgcn_s_barrier();

        // ---- k-slice 0 ----
        {
            short8 af[8], bfr[4];
            #pragma unroll
            for (int i = 0; i < 8; i++)
                af[i] = *(const short8*)&As[cur][(wm + i * 16 + l16) * 64 + swz0];
            #pragma unroll
            for (int j = 0; j < 4; j++)
                bfr[j] = *(const short8*)&Bs[cur][(wn + j * 16 + l16) * 64 + swz0];
            __builtin_amdgcn_s_waitcnt(WC_LGKM0);
            #pragma unroll
            for (int i = 0; i < 8; i++)
                #pragma unroll
                for (int j = 0; j < 4; j++)
                    acc[i][j] = __builtin_amdgcn_mfma_f32_16x16x32_bf16(
                        af[i], bfr[j], acc[i][j], 0, 0, 0);
        }
        // ---- k-slice 1 ----
        {
            short8 af[8], bfr[4];
            #pragma unroll
            for (int i = 0; i < 8; i++)
                af[i] = *(const short8*)&As[cur][(wm + i * 16 + l16) * 64 + swz1];
            #pragma unroll
            for (int j = 0; j < 4; j++)
                bfr[j] = *(const short8*)&Bs[cur][(wn + j * 16 + l16) * 64 + swz1];
            __builtin_amdgcn_s_waitcnt(WC_LGKM0);
            #pragma unroll
            for (int i = 0; i < 8; i++)
                #pragma unroll
                for (int j = 0; j < 4; j++)
                    acc[i][j] = __builtin_amdgcn_mfma_f32_16x16x32_bf16(
                        af[i], bfr[j], acc[i][j], 0, 0, 0);
        }
        __builtin_amdgcn_s_barrier();   // all reads done -> buf reusable
    }
    #undef STAGE

    // C/D layout (m89-verified): col = lane&15, row = quad*4 + reg.
    #pragma unroll
    for (int j = 0; j < 4; j++) {
        int n = n0 + wn + j * 16 + l16;
        #pragma unroll
        for (int i = 0; i < 8; i++) {
            int mrow = m0 + wm + i * 16 + quad * 4;
            #pragma unroll
            for (int rr2 = 0; rr2 < 4; rr2++)
                Cb[(size_t)(mrow + rr2) * ldc + n] = f2bf(acc[i][j][rr2]);
        }
    }
}

// ---------------------------------------------------------------------------
// bf16 MFMA GEMM, 64x64 tile (r3 structure — proven across 5 passing runs):
// triple-buffered LDS, distance-2 prefetch, single barrier per iter, XOR-8
// swizzle (conflicts=0), XCD-chunked bijective remap (FETCH 37.6->18MB).
// flags: 1 = add bias[n], 2 = accumulate into C (fp32),
//        4 = softplus(v + bias[n]) for n<1024,
//        8 = write bf16 to Cb only,
//       16 = also write bf16 to Cb (combine with 2: h-accum + bf16 copy).
// ---------------------------------------------------------------------------
__global__ __launch_bounds__(256, 3) void gemm_bf16_tile(
    const ushort_t* __restrict__ A, int lda,
    const ushort_t* __restrict__ Bt, int ldb,
    float* __restrict__ C, ushort_t* __restrict__ Cb, int ldc,
    const float* __restrict__ bias,
    int M, int N, int K, int flags)
{
    __shared__ ushort_t As[3][4096];   // 3 x 8 KB
    __shared__ ushort_t Bs[3][4096];   // 3 x 8 KB

    const int gx = gridDim.x;
    const int nwg = gx * gridDim.y;
    const int orig = blockIdx.y * gx + blockIdx.x;
    const int qq = nwg >> 3, rr = nwg & 7;
    const int xcd = orig & 7, loc = orig >> 3;
    const int swz = (xcd < rr ? xcd * (qq + 1) : rr * (qq + 1) + (xcd - rr) * qq) + loc;
    const int m0 = (swz / gx) * 64;
    const int n0 = (swz % gx) * 64;

    const int tid = threadIdx.x;
    const int w = tid >> 6;
    const int lane = tid & 63;
    const int quad = lane >> 4;
    const int l16 = lane & 15;
    const int wm = (w & 1) * 32;
    const int wn = (w >> 1) * 32;

    const int srow = tid >> 3;
    const int schunk = ((tid & 7) ^ (srow & 7)) * 8;
    const ushort_t* ga = A + (size_t)(m0 + srow) * lda + schunk;
    const ushort_t* gb = Bt + (size_t)(n0 + srow) * ldb + schunk;
    const int lofs = tid * 8;

    const int swz0 = ((0 * 4 + quad) ^ (l16 & 7)) * 8;
    const int swz1 = ((1 * 4 + quad) ^ (l16 & 7)) * 8;

    floatx4 acc[2][2] = {};
    const int nt = K >> 6;

    #define STAGE(t, b)                                         \
        do {                                                    \
            const ushort_t* pa_ = ga + (t) * 64;                \
            const ushort_t* pb_ = gb + (t) * 64;                \
            gll16(pa_, &As[(b)][lofs]);                         \
            gll16(pa_ + (size_t)32 * lda, &As[(b)][2048 + lofs]); \
            gll16(pb_, &Bs[(b)][lofs]);                         \
            gll16(pb_ + (size_t)32 * ldb, &Bs[(b)][2048 + lofs]); \
        } while (0)

    STAGE(0, 0);
    if (nt > 1) STAGE(1, 1);

    int cur = 0;
    for (int kt = 0; kt < nt; kt++) {
        if (kt + 1 < nt) __builtin_amdgcn_s_waitcnt(WC_VM4);
        else             __builtin_amdgcn_s_waitcnt(WC_VM0);
        __builtin_amdgcn_s_barrier();
        __builtin_amdgcn_sched_barrier(0);

        if (kt + 2 < nt) {
            int nb = cur + 2; if (nb >= 3) nb -= 3;
            STAGE(kt + 2, nb);
        }

        short8 af[2][2], bfr[2][2];
        #pragma unroll
        for (int i = 0; i < 2; i++) {
            const int r = wm + i * 16 + l16;
            af[0][i] = *(const short8*)&As[cur][r * 64 + swz0];
            af[1][i] = *(const short8*)&As[cur][r * 64 + swz1];
        }
        #pragma unroll
        for (int j = 0; j < 2; j++) {
            const int r = wn + j * 16 + l16;
            bfr[0][j] = *(const short8*)&Bs[cur][r * 64 + swz0];
            bfr[1][j] = *(const short8*)&Bs[cur][r * 64 + swz1];
        }
        __builtin_amdgcn_s_waitcnt(WC_LGKM0);
        __builtin_amdgcn_sched_barrier(0);

        #pragma unroll
        for (int ks = 0; ks < 2; ks++)
            #pragma unroll
            for (int i = 0; i < 2; i++)
                #pragma unroll
                for (int j = 0; j < 2; j++)
                    acc[i][j] = __builtin_amdgcn_mfma_f32_16x16x32_bf16(
                        af[ks][i], bfr[ks][j], acc[i][j], 0, 0, 0);

        cur++; if (cur == 3) cur = 0;
    }
    #undef STAGE

    // C/D layout (m89-verified): col = lane&15, row = quad*4 + reg.
    #pragma unroll
    for (int j = 0; j < 2; j++) {
        int n = n0 + wn + j * 16 + l16;
        float bv = (flags & 1) ? bias[n] : 0.f;
        bool do_sp = (flags & 4) && (n < 1024);
        float spb = do_sp ? bias[n] : 0.f;
        #pragma unroll
        for (int i = 0; i < 2; i++) {
            int mrow = m0 + wm + i * 16 + quad * 4;
            #pragma unroll
            for (int rr2 = 0; rr2 < 4; rr2++) {
                size_t idx = (size_t)(mrow + rr2) * ldc + n;
                float v = acc[i][j][rr2] + bv;
                if (do_sp) {
                    v += spb;
                    v = (v > 20.f) ? v : log1pf(__expf(v));
                }
                if (flags & 8) {
                    Cb[idx] = f2bf(v);
                } else {
                    if (flags & 2) v += C[idx];
                    C[idx] = v;
                    if (flags & 16) Cb[idx] = f2bf(v);
                }
            }
        }
    }
}

// ---------------------------------------------------------------------------
// stepA split-K GEMM: Cpart[kq] = u[:, kq*256:(kq+1)*256] @ xw_t^T (N=64).
// ---------------------------------------------------------------------------
__global__ __launch_bounds__(256, 3) void gemm_stepA(
    const ushort_t* __restrict__ A,   // [NTOK][1024] bf16 (u)
    const ushort_t* __restrict__ Bt,  // [64][1024] bf16 (xw_t)
    float* __restrict__ Cpart)        // [4][NTOK][64]
{
    __shared__ ushort_t As[3][4096];
    __shared__ ushort_t Bs[3][4096];

    const int kq = blockIdx.x;          // 0..3 (K window)
    const int m0 = blockIdx.y * 64;
    const int k0 = kq * 256;

    const int tid = threadIdx.x;
    const int w = tid >> 6;
    const int lane = tid & 63;
    const int quad = lane >> 4;
    const int l16 = lane & 15;
    const int wm = (w & 1) * 32;
    const int wn = (w >> 1) * 32;

    const int srow = tid >> 3;
    const int schunk = ((tid & 7) ^ (srow & 7)) * 8;
    const ushort_t* ga = A + (size_t)(m0 + srow) * 1024 + k0 + schunk;
    const ushort_t* gb = Bt + (size_t)srow * 1024 + k0 + schunk;
    const int lofs = tid * 8;

    const int swz0 = ((0 * 4 + quad) ^ (l16 & 7)) * 8;
    const int swz1 = ((1 * 4 + quad) ^ (l16 & 7)) * 8;

    floatx4 acc[2][2] = {};
    const int nt = 4;

    #define STAGE(t, b)                                            \
        do {                                                       \
            const ushort_t* pa_ = ga + (t) * 64;                   \
            const ushort_t* pb_ = gb + (t) * 64;                   \
            gll16(pa_, &As[(b)][lofs]);                            \
            gll16(pa_ + (size_t)32 * 1024, &As[(b)][2048 + lofs]); \
            gll16(pb_, &Bs[(b)][lofs]);                            \
            gll16(pb_ + (size_t)32 * 1024, &Bs[(b)][2048 + lofs]); \
        } while (0)

    STAGE(0, 0);
    STAGE(1, 1);

    int cur = 0;
    for (int kt = 0; kt < nt; kt++) {
        if (kt + 1 < nt) __builtin_amdgcn_s_waitcnt(WC_VM4);
        else             __builtin_amdgcn_s_waitcnt(WC_VM0);
        __builtin_amdgcn_s_barrier();
        __builtin_amdgcn_sched_barrier(0);

        if (kt + 2 < nt) {
            int nb = cur + 2; if (nb >= 3) nb -= 3;
            STAGE(kt + 2, nb);
        }

        short8 af[2][2], bfr[2][2];
        #pragma unroll
        for (int i = 0; i < 2; i++) {
            const int r = wm + i * 16 + l16;
            af[0][i] = *(const short8*)&As[cur][r * 64 + swz0];
            af[1][i] = *(const short8*)&As[cur][r * 64 + swz1];
        }
        #pragma unroll
        for (int j = 0; j < 2; j++) {
            const int r = wn + j * 16 + l16;
            bfr[0][j] = *(const short8*)&Bs[cur][r * 64 + swz0];
            bfr[1][j] = *(const short8*)&Bs[cur][r * 64 + swz1];
        }
        __builtin_amdgcn_s_waitcnt(WC_LGKM0);
        __builtin_amdgcn_sched_barrier(0);

        #pragma unroll
        for (int ks = 0; ks < 2; ks++)
            #pragma unroll
            for (int i = 0; i < 2; i++)
                #pragma unroll
                for (int j = 0; j < 2; j++)
                    acc[i][j] = __builtin_amdgcn_mfma_f32_16x16x32_bf16(
                        af[ks][i], bfr[ks][j], acc[i][j], 0, 0, 0);

        cur++; if (cur == 3) cur = 0;
    }
    #undef STAGE

    float* Cp = Cpart + (size_t)kq * NTOK * 64;
    #pragma unroll
    for (int j = 0; j < 2; j++) {
        int n = wn + j * 16 + l16;
        #pragma unroll
        for (int i = 0; i < 2; i++) {
            int mrow = m0 + wm + i * 16 + quad * 4;
            #pragma unroll
            for (int rr2 = 0; rr2 < 4; rr2++)
                Cp[(size_t)(mrow + rr2) * 64 + n] = acc[i][j][rr2];
        }
    }
}

// ---------------------------------------------------------------------------
// reduce_dblr: dblr = sum of 4 split-K partials (fp32) + bf16 copy for stepB.
// ---------------------------------------------------------------------------
__global__ __launch_bounds__(256) void reduce_dblr(
    const float* __restrict__ part, float* __restrict__ dblr,
    ushort_t* __restrict__ dblr_bf)
{
    const int i = blockIdx.x * 256 + threadIdx.x;
    const size_t st = (size_t)NTOK * 64;
    float s = part[i] + part[i + st] + part[i + 2 * st] + part[i + 3 * st];
    dblr[i] = s;
    dblr_bf[i] = f2bf(s);
}

// ---------------------------------------------------------------------------
// build_w2t: W2t[l][n][k] = (k<32) ? bf16(dt_w[l][k][n]) : 0.
// (Pad MUST be written every launch: d_ws is re-poisoned to 0xAA.)
// ---------------------------------------------------------------------------
__global__ __launch_bounds__(256) void build_w2t_kernel(
    const float* __restrict__ dt_w, ushort_t* __restrict__ w2t)
{
    const int idx = blockIdx.x * 256 + threadIdx.x;
    const int k = idx & 63;
    const int n = (idx >> 6) & 1023;
    const int l = idx >> 16;
    ushort_t v = 0;
    if (k < 32)
        v = f2bf(dt_w[((size_t)l * DT_RANK + k) * D_INNER + n]);
    w2t[((size_t)l * 1024 + n) * 64 + k] = v;
}

// ---------------------------------------------------------------------------
// Batched transpose+cast: z-dim = layer. in[l][K][N] -> out[l][N][K] bf16.
// ---------------------------------------------------------------------------
__global__ __launch_bounds__(256) void transpose_cast_b(
    const float* __restrict__ in0, ushort_t* __restrict__ out0, int K, int N,
    size_t in_ls, size_t out_ls)
{
    const float* in = in0 + (size_t)blockIdx.z * in_ls;
    ushort_t* out = out0 + (size_t)blockIdx.z * out_ls;
    __shared__ float tile[32][33];
    const int n0 = blockIdx.x * 32, k0 = blockIdx.y * 32;
    const int tx = threadIdx.x & 31, ty = threadIdx.x >> 5;
    #pragma unroll
    for (int i = 0; i < 4; i++)
        tile[ty + i * 8][tx] = in[(size_t)(k0 + ty + i * 8) * N + n0 + tx];
    __syncthreads();
    #pragma unroll
    for (int i = 0; i < 4; i++)
        out[(size_t)(n0 + ty + i * 8) * K + k0 + tx] = f2bf(tile[tx][ty + i * 8]);
}

// ---------------------------------------------------------------------------
__global__ __launch_bounds__(256) void cast_bf16_kernel(
    const float* __restrict__ in, ushort_t* __restrict__ out)
{
    const int i = blockIdx.x * 256 + threadIdx.x;
    out[i] = f2bf(in[i]);
}

// ---------------------------------------------------------------------------
__global__ __launch_bounds__(256) void rmsnorm_kernel(
    const float* __restrict__ x, const float* __restrict__ w,
    ushort_t* __restrict__ y)
{
    const int row = blockIdx.x;
    const float* xr = x + (size_t)row * D_MODEL;
    ushort_t* yr = y + (size_t)row * D_MODEL;
    const int tid = threadIdx.x;

    float v0 = xr[tid], v1 = xr[tid + 256];
    float ss = v0 * v0 + v1 * v1;
    #pragma unroll
    for (int off = 32; off > 0; off >>= 1) ss += __shfl_down(ss, off);

    __shared__ float wsum[4];
    __shared__ float scale_s;
    int wid = tid >> 6, lane = tid & 63;
    if (lane == 0) wsum[wid] = ss;
    __syncthreads();
    if (tid == 0) {
        float tot = wsum[0] + wsum[1] + wsum[2] + wsum[3];
        scale_s = 1.0f / sqrtf(tot / (float)D_MODEL + 1e-5f);
    }
    __syncthreads();
    float sc = scale_s;
    yr[tid] = f2bf(v0 * sc * w[tid]);
    yr[tid + 256] = f2bf(v1 * sc * w[tid + 256]);
}

// ---------------------------------------------------------------------------
// Causal dwconv (K=4) + bias + silu. Reads bf16 xz (stride 2048, xp plane),
// writes bf16 u.
// ---------------------------------------------------------------------------
__global__ __launch_bounds__(256) void conv_silu_kernel(
    const ushort_t* __restrict__ xz, const float* __restrict__ w,
    const float* __restrict__ bconv, ushort_t* __restrict__ outb)
{
    const int idx = blockIdx.x * 256 + threadIdx.x;
    const int d = idx & (D_INNER - 1);
    const int t = (idx >> 10) & (SEQ - 1);
    const int row = idx >> 10;
    const ushort_t* base = xz + (size_t)row * 2048 + d;

    float s = 0.f;
    #pragma unroll
    for (int k = 0; k < KCONV; k++) {
        int tt = t + k - (KCONV - 1);
        if (tt >= 0)
            s = fmaf(bf2f(base[(ptrdiff_t)(k - (KCONV - 1)) * 2048]), w[d * KCONV + k], s);
    }
    s += bconv[d];
    float r = s / (1.f + __expf(-s));
    outb[idx] = f2bf(r);
}

// ---------------------------------------------------------------------------
// Chunked selective scan (3 passes), CLEN=32.
// dt in dtb (stride 1024, already softplus'ed); B/C in bc (stride 64):
// bc[row][32+n]=B[n], bc[row][48+n]=C[n]. u bf16 in ub; z bf16 in xz[:,1024:].
// ---------------------------------------------------------------------------
__global__ __launch_bounds__(256) void scan_pass1(
    const float* __restrict__ dtb, const float* __restrict__ bc,
    const ushort_t* __restrict__ ub, const float* __restrict__ A_log,
    float* __restrict__ hfin, float* __restrict__ sumdt)
{
    const int tid = threadIdx.x;
    const int b = blockIdx.x >> 7;
    const int p = (blockIdx.x >> 2) & 31;
    const int d = ((blockIdx.x & 3) << 8) + tid;
    const int t0 = p * CLEN;

    float A[D_STATE];
    #pragma unroll
    for (int n = 0; n < D_STATE; n++) A[n] = -expf(A_log[d * D_STATE + n]);

    float h[D_STATE] = {};
    float sdt = 0.f;

    const float* dtp = dtb + ((size_t)b * SEQ + t0) * 1024 + d;
    const float* bp  = bc + ((size_t)b * SEQ + t0) * 64 + 32;
    const ushort_t* up = ub + ((size_t)b * SEQ + t0) * D_INNER + d;

    for (int t = 0; t < CLEN; t++) {
        float dtv = dtp[(size_t)t * 1024];
        float uv  = bf2f(up[(size_t)t * D_INNER]);
        float dtu = dtv * uv;
        sdt += dtv;
        #pragma unroll
        for (int n = 0; n < D_STATE; n++)
            h[n] = fmaf(__expf(dtv * A[n]), h[n], dtu * bp[t * 64 + n]);
    }

    size_t base = (size_t)(b * PCH + p) * D_STATE * D_INNER + d;
    #pragma unroll
    for (int n = 0; n < D_STATE; n++) hfin[base + (size_t)n * D_INNER] = h[n];
    sumdt[(size_t)(b * PCH + p) * D_INNER + d] = sdt;
}

// preload all 32 chunk-final states + sumdt (independent loads), then the
// serial recurrence runs as pure VALU with fire-and-forget writes (r9 win).
__global__ __launch_bounds__(256) void scan_pass2(
    const float* __restrict__ A_log, const float* __restrict__ sumdt,
    float* __restrict__ hc)
{
    const int tid = threadIdx.x;
    const int b = blockIdx.x >> 6;
    const int n = (blockIdx.x >> 2) & 15;
    const int d = ((blockIdx.x & 3) << 8) + tid;

    const float Aval = -expf(A_log[d * D_STATE + n]);

    float fin[PCH], sd[PCH];
    #pragma unroll
    for (int p = 0; p < PCH; p++) {
        fin[p] = hc[((size_t)(b * PCH + p) * D_STATE + n) * D_INNER + d];
        sd[p]  = sumdt[(size_t)(b * PCH + p) * D_INNER + d];
    }
    float h = 0.f;
    #pragma unroll
    for (int p = 0; p < PCH; p++) {
        hc[((size_t)(b * PCH + p) * D_STATE + n) * D_INNER + d] = h;
        h = fmaf(__expf(Aval * sd[p]), h, fin[p]);
    }
}

// pass3: u (bf16, in ub) read then overwritten IN PLACE with y*silu(z).
__global__ __launch_bounds__(256) void scan_pass3(
    const float* __restrict__ dtb, const float* __restrict__ bc,
    const ushort_t* __restrict__ xz, const float* __restrict__ A_log,
    const float* __restrict__ Dp, const float* __restrict__ hstart,
    ushort_t* ub)
{
    const int tid = threadIdx.x;
    const int b = blockIdx.x >> 7;
    const int p = (blockIdx.x >> 2) & 31;
    const int d = ((blockIdx.x & 3) << 8) + tid;
    const int t0 = p * CLEN;

    float A[D_STATE];
    #pragma unroll
    for (int n = 0; n < D_STATE; n++) A[n] = -expf(A_log[d * D_STATE + n]);
    const float Dv = Dp[d];

    float h[D_STATE];
    size_t base = (size_t)(b * PCH + p) * D_STATE * D_INNER + d;
    #pragma unroll
    for (int n = 0; n < D_STATE; n++) h[n] = hstart[base + (size_t)n * D_INNER];

    const float* dtp = dtb + ((size_t)b * SEQ + t0) * 1024 + d;
    const float* bp  = bc + ((size_t)b * SEQ + t0) * 64 + 32;
    const ushort_t* zp = xz + ((size_t)b * SEQ + t0) * 2048 + 1024 + d;
    ushort_t* up = ub + ((size_t)b * SEQ + t0) * D_INNER + d;

    for (int t = 0; t < CLEN; t++) {
        float dtv = dtp[(size_t)t * 1024];
        float uv  = bf2f(up[(size_t)t * D_INNER]);
        float zv  = bf2f(zp[(size_t)t * 2048]);
        float dtu = dtv * uv;
        float y = 0.f;
        #pragma unroll
        for (int n = 0; n < D_STATE; n++) {
            h[n] = fmaf(__expf(dtv * A[n]), h[n], dtu * bp[t * 64 + n]);
            y = fmaf(h[n], bp[t * 64 + 16 + n], y);
        }
        float res = fmaf(uv, Dv, y);
        res *= zv / (1.f + __expf(-zv));
        up[(size_t)t * D_INNER] = f2bf(res);
    }
}

// ---------------------------------------------------------------------------
__global__ __launch_bounds__(256) void softmax_kernel(
    const float* __restrict__ in, float* __restrict__ out)
{
    const int idx = blockIdx.x * 256 + threadIdx.x;
    float v = in[idx];
    float m = v;
    #pragma unroll
    for (int off = 16; off > 0; off >>= 1) m = fmaxf(m, __shfl_xor(m, off, 32));
    float e = expf(v - m);
    float s = e;
    #pragma unroll
    for (int off = 16; off > 0; off >>= 1) s += __shfl_xor(s, off, 32);
    out[idx] = e / s;
}

// ---------------------------------------------------------------------------
extern "C" void kernel_launch(void* const* d_in, const int* in_sizes, int n_in,
                              void* d_out, int out_size, void* d_ws, size_t ws_size,
                              hipStream_t stream)
{
    const float* x       = (const float*)d_in[0];
    const float* lin1_w  = (const float*)d_in[1];
    const float* lin1_b  = (const float*)d_in[2];
    const float* norm_w  = (const float*)d_in[3];
    const float* in_w    = (const float*)d_in[4];
    const float* conv_w  = (const float*)d_in[5];
    const float* conv_b  = (const float*)d_in[6];
    const float* xproj_w = (const float*)d_in[7];
    const float* dt_w    = (const float*)d_in[8];
    const float* dt_b    = (const float*)d_in[9];
    const float* A_log   = (const float*)d_in[10];
    const float* Dp      = (const float*)d_in[11];
    const float* out_w   = (const float*)d_in[12];
    const float* lin2_w  = (const float*)d_in[13];
    const float* lin2_b  = (const float*)d_in[14];
    float* outp = (float*)d_out;
    (void)ws_size; (void)in_sizes; (void)n_in; (void)out_size;

    float* ws = (float*)d_ws;
    const size_t F1M = 1u << 20;
    float* h     = ws;                                  // 2M fl
    float* dtb   = h + 2 * F1M;                         // 4M fl (dt; lin2 logits)
    float* dblr  = dtb + 4 * F1M;                       // 256K fl
    float* dpart = dblr + (size_t)NTOK * 64;            // 1M fl (4 split-K partials)
    float* sumdt = dpart + (size_t)4 * NTOK * 64;       // 128K fl
    float* hfin  = sumdt + (size_t)BATCH * PCH * D_INNER;  // 2M fl
    ushort_t* xzb     = (ushort_t*)(hfin + 2 * F1M);       // 8M us (xp|z, 2048)
    ushort_t* hn_bf   = xzb + 8 * F1M;                     // 2M us
    ushort_t* xb      = hn_bf + 2 * F1M;                   // 4M us
    ushort_t* dblr_bf = xb + 4 * F1M;                      // 256K us
    ushort_t* lin1_wt = dblr_bf + (size_t)NTOK * 64;       // 512*1024
    ushort_t* in_wt   = lin1_wt + (size_t)512 * 1024;      // 4*2048*512
    ushort_t* out_wt  = in_wt + (size_t)4 * 2048 * 512;    // 4*512*1024
    ushort_t* lin2_wt = out_wt + (size_t)4 * 512 * 1024;   // 1024*512
    ushort_t* xw_t    = lin2_wt + (size_t)1024 * 512;      // 4*64*1024
    ushort_t* w2t     = xw_t + (size_t)4 * 64 * 1024;      // 4*1024*64

    dim3 blk(256);

    // --- weight prep (batched: 6 launches) ---
    transpose_cast_b<<<dim3(512 / 32, 1024 / 32, 1), blk, 0, stream>>>(
        lin1_w, lin1_wt, LATENT, D_MODEL, 0, 0);
    transpose_cast_b<<<dim3(2048 / 32, 512 / 32, N_LAYERS), blk, 0, stream>>>(
        in_w, in_wt, 512, 2048, (size_t)512 * 2048, (size_t)2048 * 512);
    transpose_cast_b<<<dim3(512 / 32, 1024 / 32, N_LAYERS), blk, 0, stream>>>(
        out_w, out_wt, 1024, 512, (size_t)1024 * 512, (size_t)512 * 1024);
    transpose_cast_b<<<dim3(64 / 32, 1024 / 32, N_LAYERS), blk, 0, stream>>>(
        xproj_w, xw_t, 1024, 64, (size_t)1024 * 64, (size_t)64 * 1024);
    transpose_cast_b<<<dim3(1024 / 32, 512 / 32, 1), blk, 0, stream>>>(
        lin2_w, lin2_wt, D_MODEL, LATENT, 0, 0);
    build_w2t_kernel<<<dim3((N_LAYERS * 1024 * 64) / 256), blk, 0, stream>>>(
        dt_w, w2t);

    // x -> bf16
    cast_bf16_kernel<<<dim3((NTOK * LATENT) / 256), blk, 0, stream>>>(x, xb);

    // lin1: h = x_bf @ lin1_wt^T + b  (fp32 out; 8x64=512 blocks)
    gemm_bf16_tile<<<dim3(D_MODEL / 64, NTOK / 64), blk, 0, stream>>>(
        xb, LATENT, lin1_wt, LATENT, h, nullptr, D_MODEL, lin1_b,
        NTOK, D_MODEL, LATENT, 1);

    for (int l = 0; l < N_LAYERS; l++) {
        const float* nw = norm_w + (size_t)l * D_MODEL;
        const float* cw = conv_w + (size_t)l * D_INNER * KCONV;
        const float* cb = conv_b + (size_t)l * D_INNER;
        const float* db = dt_b + (size_t)l * D_INNER;
        const float* al = A_log + (size_t)l * D_INNER * D_STATE;
        const float* dp = Dp + (size_t)l * D_INNER;
        const ushort_t* iwt = in_wt + (size_t)l * 2048 * 512;
        const ushort_t* owt = out_wt + (size_t)l * 512 * 1024;
        const ushort_t* xwt = xw_t + (size_t)l * 64 * 1024;
        const ushort_t* w2  = w2t + (size_t)l * 1024 * 64;

        rmsnorm_kernel<<<dim3(NTOK), blk, 0, stream>>>(h, nw, hn_bf);

        // fused in-proj: xzb = hn @ in_w[l] (bf16 out; 256^2 2-phase,
        // 8x16 = 128 blocks, 512 threads)
        gemm_bf16_t256<<<dim3(2048 / 256, NTOK / 256), dim3(512), 0, stream>>>(
            hn_bf, D_MODEL, iwt, D_MODEL, xzb, 2048, NTOK, 2048, D_MODEL);

        // conv + silu: xzb[:, :1024] -> xb (bf16 u)
        conv_silu_kernel<<<dim3((NTOK * D_INNER) / 256), blk, 0, stream>>>(
            xzb, cw, cb, xb);

        // xproj step A (split-K x4): dpart[kq] = u @ xw_t^T  (4x64=256 blocks)
        gemm_stepA<<<dim3(4, NTOK / 64), blk, 0, stream>>>(xb, xwt, dpart);
        // reduce partials -> dblr fp32 (B/C for scan) + dblr_bf for stepB
        reduce_dblr<<<dim3((NTOK * 64) / 256), blk, 0, stream>>>(
            dpart, dblr, dblr_bf);

        // step B: dtb = softplus(dblr_bf @ W2t^T + dt_b)  (N=1024, K=64,
        // one K-tile; W2t rows 32..63 zero -> B/C cols contribute 0).
        gemm_bf16_tile<<<dim3(1024 / 64, NTOK / 64), blk, 0, stream>>>(
            dblr_bf, 64, w2, 64, dtb, nullptr, 1024, db,
            NTOK, 1024, 64, 4);

        // chunked scan; pass3 overwrites xb in place with y*silu(z)
        scan_pass1<<<dim3(BATCH * PCH * (D_INNER / 256)), blk, 0, stream>>>(
            dtb, dblr, xb, al, hfin, sumdt);
        scan_pass2<<<dim3(BATCH * D_STATE * (D_INNER / 256)), blk, 0, stream>>>(
            al, sumdt, hfin);
        scan_pass3<<<dim3(BATCH * PCH * (D_INNER / 256)), blk, 0, stream>>>(
            dtb, dblr, xzb, al, dp, hfin, xb);

        // h += y_bf @ out_wt^T  (fp32 accumulate; 8x64=512 blocks).
        // Last layer: flags 2|16 also emits bf16(h) into hn_bf -> feeds
        // lin2 directly, dropping the separate h->bf16 cast launch.
        gemm_bf16_tile<<<dim3(D_MODEL / 64, NTOK / 64), blk, 0, stream>>>(
            xb, D_INNER, owt, D_INNER, h, hn_bf, D_MODEL, nullptr,
            NTOK, D_MODEL, D_INNER, (l == N_LAYERS - 1) ? 18 : 2);
    }

    // lin2 (logits into dtb) reads bf16 h from hn_bf, then softmax
    gemm_bf16_tile<<<dim3(LATENT / 64, NTOK / 64), blk, 0, stream>>>(
        hn_bf, D_MODEL, lin2_wt, D_MODEL, dtb, nullptr, LATENT, lin2_b,
        NTOK, LATENT, D_MODEL, 1);
    softmax_kernel<<<dim3((NTOK * LATENT) / 256), blk, 0, stream>>>(dtb, outp);
}